// Round 8
// baseline (781.951 us; speedup 1.0000x reference)
//
#include <hip/hip_runtime.h>
#include <hip/hip_bf16.h>

// VQ-VAE forward — NHWC bf16 intermediates, MFMA (16x16x32 bf16) for all convs.
// Outputs: [1.25*vq_mse, recon_mse, recon_mse]
//
// MFMA lane layouts (gfx950, HW-verified per guide):
//   A: m = lane&15, k = (lane>>4)*8 + j     (8 bf16 / lane)
//   B: n = lane&15, k = (lane>>4)*8 + j
//   D: n = lane&15, m = (lane>>4)*4 + reg   (4 f32 / lane)
//
// CHANNEL-INTERLEAVED storage: a producer with U=Cc/16 tiles stores tile u,
// column n16 (logical co = u*16+n16) at memory channel m = n16*U+u; consumers
// permute ci in weight prep: logical l(m) = (m%U)*16 + m/U.
//
// dec2+dec3 FUSED (dec23_k). R13: 1 atomic/block (580->409). R14: class-
// sequential stage 1 (409->323). R15: XCD swizzle (FETCH -55%, flat).
// R16: LDS traffic -40% (flat). R17/R18: occupancy probes (spill / narrow-tile
// overhead; occupancy 43% did NOT help -> latency theory dead).
// R19: LOAD BATCHING. Cross-round invariant: per-wave latency ~60-72k cy ==
// ~126 stage-1 global loads x ~500cy FULLY SERIALIZED (TAP macro consumed
// each load immediately; VGPR 60-84 left no hoisting room). Restructure:
// cell OUTER (batch all 8 A-frags per cell — all 9 taps reuse them),
// classes inner with per-class B-batches (4-16 loads in flight). Exposed
// waits 126 -> ~25/wave. launch_bounds(256,3): 170-VGPR headroom, peak ~135.
// Geometry back to R16's 128-col tile (best measured: 319us).
//
// d1p [B][129][129][64]: interior (0,0)..(127,127); pad row/col 128 = 0.

typedef __attribute__((ext_vector_type(8))) short bf16x8;
typedef __attribute__((ext_vector_type(4))) float f32x4;
typedef __attribute__((ext_vector_type(4))) int i32x4;
typedef unsigned short ushort_t;

__device__ __forceinline__ ushort_t f2bf(float v) {
    __hip_bfloat16 h = __float2bfloat16(v);
    return *(ushort_t*)&h;
}
__device__ __forceinline__ float bf2f(ushort_t u) {
    __hip_bfloat16 h = *(__hip_bfloat16*)&u;
    return __bfloat162float(h);
}
__device__ __forceinline__ unsigned pack2r(float a, float b) {   // relu+pack
    return (unsigned)f2bf(fmaxf(a, 0.f)) | ((unsigned)f2bf(fmaxf(b, 0.f)) << 16);
}
// XCD-chunked bijective remap (requires nwg%8==0).
__device__ __forceinline__ int xcd_chunk(int flat, int nwg) {
    return (flat & 7) * (nwg >> 3) + (flat >> 3);
}
// DPP row-rotate of a 16B fragment within each 16-lane row.
// row_ror:N -> dst[n] = src[(n-N) mod 16].  0x121 = ror:1, 0x12F = ror:15.
#define ROR_FRAG(dst, src, CTRL)                                        \
    {                                                                   \
        i32x4 _a = __builtin_bit_cast(i32x4, src), _r;                  \
        _r[0] = __builtin_amdgcn_mov_dpp(_a[0], CTRL, 0xF, 0xF, false); \
        _r[1] = __builtin_amdgcn_mov_dpp(_a[1], CTRL, 0xF, 0xF, false); \
        _r[2] = __builtin_amdgcn_mov_dpp(_a[2], CTRL, 0xF, 0xF, false); \
        _r[3] = __builtin_amdgcn_mov_dpp(_a[3], CTRL, 0xF, 0xF, false); \
        dst = __builtin_bit_cast(bf16x8, _r);                           \
    }

// Accumulator layout (fp32, 4096 floats = 16 KB at workspace base):
//   vq  partials: acc[slot*32],        slot = 0..63   (128 B apart)
//   mse partials: acc[2048 + slot*32], slot = 0..63
//
// Transformed-weight layout in wbuf (elements of bf16, at base+16384):
//   W1T  @ 0      [co32][k32]            (k=ci*9+kh*3+kw, pad 27->32)
//   W2T  @ 1024   [t9][co64][ci32]       (ci permuted: l2(ci))
//   WD1  @ 19456  [t9][co64][k32]        (k<16 = ci natural, else 0)
//   WD2  @ 37888  [t9][kc2][co32][ci32]  (ci permuted: l4(kc*32+ci))
//   WD3  @ 56320  [t9][co16][ci32]       (taps FLIPPED: src 8-t; ci perm l2; co>=3 -> 0)
//   cn (fp32, 512) @ byte offset 121856 within wbuf

__global__ void zero_k(float* __restrict__ acc) {
    acc[blockIdx.x * 256 + threadIdx.x] = 0.f;
}

__global__ __launch_bounds__(256) void prep_k(
        const float* __restrict__ ew1, const float* __restrict__ ew2,
        const float* __restrict__ dw1, const float* __restrict__ dw2,
        const float* __restrict__ dw3, const float* __restrict__ cb,
        ushort_t* __restrict__ wt, float* __restrict__ cn) {
    int idx = blockIdx.x * 256 + threadIdx.x;
    if (idx < 1024) {
        int co = idx >> 5, k = idx & 31;
        wt[idx] = (k < 27) ? f2bf(ew1[co * 27 + k]) : (ushort_t)0;
    } else if (idx < 19456) {
        int i = idx - 1024;
        int t = i >> 11, co = (i >> 5) & 63, ci = i & 31;
        int lci = ((ci & 1) << 4) | (ci >> 1);                 // l2 (conv1 U=2)
        wt[idx] = f2bf(ew2[co * 288 + lci * 9 + t]);
    } else if (idx < 37888) {
        int i = idx - 19456;
        int t = i >> 11, co = (i >> 5) & 63, k = i & 31;
        wt[idx] = (k < 16) ? f2bf(dw1[k * 576 + co * 9 + t]) : (ushort_t)0;
    } else if (idx < 56320) {
        int i = idx - 37888;
        int t = i >> 11, kc = (i >> 10) & 1, co = (i >> 5) & 31, ci = i & 31;
        int m = kc * 32 + ci;
        int lci = ((m & 3) << 4) | (m >> 2);                   // l4 (dec1 U=4)
        wt[idx] = f2bf(dw2[lci * 288 + co * 9 + t]);
    } else if (idx < 60928) {
        int i = idx - 56320;
        int t = i >> 9, co = (i >> 5) & 15, ci = i & 31;
        int lci = ((ci & 1) << 4) | (ci >> 1);                 // l2 (dec2 U=2)
        wt[idx] = (co < 3) ? f2bf(dw3[lci * 27 + co * 9 + (8 - t)]) : (ushort_t)0;
    } else if (idx < 61440) {
        int k = idx - 60928;
        float s = 0.f;
        #pragma unroll
        for (int d = 0; d < 16; ++d) { float v = cb[k * 16 + d]; s += v * v; }
        cn[k] = s;
    }
}

// ---------------- zero the pad borders of d1p (one block per image) ---------
__global__ __launch_bounds__(256) void pad_k(ushort_t* __restrict__ d1p) {
    const int img = blockIdx.x, tid = threadIdx.x;
    const uint4 z = (uint4){0, 0, 0, 0};
    uint4* b1 = (uint4*)(d1p + (size_t)img * 1065024);   // 129*129*64 elems
    for (int i = tid; i < 1032; i += 256) b1[132096 + i] = z;   // row 128
    for (int i = tid; i < 1024; i += 256) {                     // col 128
        int r = i >> 3, u = i & 7;
        b1[(r * 129 + 128) * 8 + u] = z;
    }
}

// ---------------- conv1 MFMA: x NCHW fp32 -> a1 [B,128,128,32] (interleaved)
__global__ __launch_bounds__(256, 4) void conv1_k(const float* __restrict__ x,
        const ushort_t* __restrict__ wt, const float* __restrict__ bias,
        ushort_t* __restrict__ a1) {
    const int L = xcd_chunk(blockIdx.y, gridDim.y);
    const int b = L >> 7, oh = L & 127;
    const int tid = threadIdx.x;
    __shared__ __align__(16) ushort_t sX[9 * 264];   // [ci*3+kh][iw+1 (258 used)]
    __shared__ int sOff[32];
    for (int i = tid; i < 9 * 264 / 2; i += 256) ((unsigned*)sX)[i] = 0u;
    if (tid < 32) {
        int k = tid, off = 0;
        if (k < 27) { int ci = k / 9, r9 = k % 9, kh = r9 / 3, kw = r9 % 3;
                      off = (ci * 3 + kh) * 264 + kw; }
        sOff[tid] = off;
    }
    __syncthreads();
    #pragma unroll
    for (int it = 0; it < 9; ++it) {
        int slot = it * 256 + tid;                  // 2304 = 3ci * 3kh * 256iw
        int ci = slot / 768, r = slot % 768, kh = r >> 8, iw = r & 255;
        int ih = 2 * oh + kh - 1;
        float v = ((unsigned)ih < 256u) ? x[(long)(b * 3 + ci) * 65536 + ih * 256 + iw] : 0.f;
        sX[(ci * 3 + kh) * 264 + iw + 1] = f2bf(v);
    }
    __syncthreads();
    const int lane = tid & 63, wave = tid >> 6, q = lane >> 4, n16 = lane & 15;
    bf16x8 Bw[2];
    #pragma unroll
    for (int u = 0; u < 2; ++u)
        Bw[u] = *(const bf16x8*)(wt + (u * 16 + n16) * 32 + q * 8);
    f32x4 acc[2][2];
    #pragma unroll
    for (int u = 0; u < 2; ++u) {
        float bz = bias[u * 16 + n16];
        acc[0][u] = (f32x4){bz, bz, bz, bz};
        acc[1][u] = (f32x4){bz, bz, bz, bz};
    }
    #pragma unroll
    for (int mf = 0; mf < 2; ++mf) {
        const int m2 = 2 * (wave * 32 + mf * 16 + n16);
        ushort_t av[8];
        #pragma unroll
        for (int j = 0; j < 8; ++j) {
            int k = q * 8 + j;
            av[j] = (k < 27) ? sX[sOff[k] + m2] : (ushort_t)0;
        }
        bf16x8 A = *(bf16x8*)av;
        #pragma unroll
        for (int u = 0; u < 2; ++u)
            acc[mf][u] = __builtin_amdgcn_mfma_f32_16x16x32_bf16(A, Bw[u], acc[mf][u], 0, 0, 0);
    }
    #pragma unroll
    for (int mf = 0; mf < 2; ++mf)
        #pragma unroll
        for (int r = 0; r < 4; ++r) {
            int ow = wave * 32 + mf * 16 + q * 4 + r;
            *(unsigned*)(a1 + ((long)(b * 128 + oh) * 128 + ow) * 32 + n16 * 2) =
                pack2r(acc[mf][0][r], acc[mf][1][r]);
        }
}

// ---------------- conv2 MFMA: a1 -> a2 [B,64,64,64] (interleaved) -----------
__global__ __launch_bounds__(256, 4) void conv2_k(const ushort_t* __restrict__ a1,
        const ushort_t* __restrict__ wt, const float* __restrict__ bias,
        ushort_t* __restrict__ a2) {
    const int L = xcd_chunk(blockIdx.y, gridDim.y);
    const int b = L >> 6, oh = L & 63;
    const int tid = threadIdx.x;
    // parity-split: [kh3][p2][c66][ci32 pad40]
    __shared__ __align__(16) ushort_t sA[3 * 2 * 66 * 40];
    uint4* z4 = (uint4*)sA;
    #pragma unroll
    for (int it = 0; it < 8; ++it) {
        int slot = it * 256 + tid;
        if (slot < 1980) z4[slot] = (uint4){0, 0, 0, 0};
    }
    __syncthreads();
    #pragma unroll
    for (int it = 0; it < 6; ++it) {
        int slot = it * 256 + tid;                    // 1536 = 3kh*128iw*4
        if (slot < 1536) {
            int kh = slot >> 9, rem = slot & 511, iw = rem >> 2, ci8 = (rem & 3) << 3;
            int ih = 2 * oh + kh - 1;
            if ((unsigned)ih < 128u) {
                uint4 v = *(const uint4*)(a1 + ((long)(b * 128 + ih) * 128 + iw) * 32 + ci8);
                int idx = iw + 2, p = idx & 1, c = idx >> 1;
                *(uint4*)&sA[((kh * 2 + p) * 66 + c) * 40 + ci8] = v;
            }
        }
    }
    __syncthreads();
    const int lane = tid & 63, wave = tid >> 6, q = lane >> 4, n16 = lane & 15;
    f32x4 acc[4];
    #pragma unroll
    for (int u = 0; u < 4; ++u) {
        float bz = bias[u * 16 + n16];
        acc[u] = (f32x4){bz, bz, bz, bz};
    }
    const int ow = wave * 16 + n16;   // A row (m)
    #pragma unroll
    for (int t = 0; t < 9; ++t) {
        const int kh = t / 3, kw = t % 3;
        const int p = (kw == 1) ? 0 : 1;
        const int c = (kw == 0) ? ow : ow + 1;
        bf16x8 A = *(bf16x8*)&sA[((kh * 2 + p) * 66 + c) * 40 + q * 8];
        #pragma unroll
        for (int u = 0; u < 4; ++u) {
            bf16x8 B = *(const bf16x8*)(wt + 1024 + t * 2048 + (u * 16 + n16) * 32 + q * 8);
            acc[u] = __builtin_amdgcn_mfma_f32_16x16x32_bf16(A, B, acc[u], 0, 0, 0);
        }
    }
    #pragma unroll
    for (int r = 0; r < 4; ++r) {
        int owo = wave * 16 + q * 4 + r;
        uint2 pk;
        pk.x = pack2r(acc[0][r], acc[1][r]);
        pk.y = pack2r(acc[2][r], acc[3][r]);
        *(uint2*)(a2 + ((long)(b * 64 + oh) * 64 + owo) * 64 + n16 * 4) = pk;
    }
}

// ---------------- conv3 (1x1) + VQ + loss, 2 px/thread ----------------------
__global__ __launch_bounds__(256) void conv3_vq_k(const ushort_t* __restrict__ a2,
        const float* __restrict__ w3, const float* __restrict__ b3,
        const float* __restrict__ cb, const float* __restrict__ cn,
        ushort_t* __restrict__ e, float* __restrict__ acc) {
    const int base = blockIdx.x * 512 + threadIdx.x;   // px0 = base, px1 = base+256
    __shared__ float sred[4];
    float z[2][16];
    #pragma unroll
    for (int p = 0; p < 2; ++p)
        #pragma unroll
        for (int d = 0; d < 16; ++d) z[p][d] = b3[d];
    #pragma unroll
    for (int p = 0; p < 2; ++p) {
        const ushort_t* arow = a2 + (long)(base + p * 256) * 64;
        #pragma unroll
        for (int c8 = 0; c8 < 8; ++c8) {
            uint4 raw = *(const uint4*)(arow + c8 * 8);
            ushort_t us[8];
            *(uint4*)us = raw;
            #pragma unroll
            for (int j = 0; j < 8; ++j) {
                int m = c8 * 8 + j;
                int lci = ((m & 3) << 4) | (m >> 2);          // l4
                float a = bf2f(us[j]);
                #pragma unroll
                for (int d = 0; d < 16; ++d)
                    z[p][d] = fmaf(a, w3[d * 64 + lci], z[p][d]);
            }
        }
    }
    const float4* cb4 = (const float4*)cb;
    float best0 = 1e30f, best1 = 1e30f; int bi0 = 0, bi1 = 0;
    for (int k = 0; k < 512; ++k) {
        float4 c0 = cb4[k * 4 + 0], c1 = cb4[k * 4 + 1];
        float4 c2 = cb4[k * 4 + 2], c3 = cb4[k * 4 + 3];
        float nk = cn[k];
        float d0 = z[0][0]*c0.x + z[0][1]*c0.y + z[0][2]*c0.z + z[0][3]*c0.w
                 + z[0][4]*c1.x + z[0][5]*c1.y + z[0][6]*c1.z + z[0][7]*c1.w
                 + z[0][8]*c2.x + z[0][9]*c2.y + z[0][10]*c2.z + z[0][11]*c2.w
                 + z[0][12]*c3.x + z[0][13]*c3.y + z[0][14]*c3.z + z[0][15]*c3.w;
        float d1 = z[1][0]*c0.x + z[1][1]*c0.y + z[1][2]*c0.z + z[1][3]*c0.w
                 + z[1][4]*c1.x + z[1][5]*c1.y + z[1][6]*c1.z + z[1][7]*c1.w
                 + z[1][8]*c2.x + z[1][9]*c2.y + z[1][10]*c2.z + z[1][11]*c2.w
                 + z[1][12]*c3.x + z[1][13]*c3.y + z[1][14]*c3.z + z[1][15]*c3.w;
        float dist0 = nk - 2.f * d0, dist1 = nk - 2.f * d1;
        if (dist0 < best0) { best0 = dist0; bi0 = k; }
        if (dist1 < best1) { best1 = dist1; bi1 = k; }
    }
    float lsum = 0.f;
    #pragma unroll
    for (int d = 0; d < 16; ++d) {
        float q0 = cb[bi0 * 16 + d], q1 = cb[bi1 * 16 + d];
        float f0 = q0 - z[0][d], f1 = q1 - z[1][d];
        lsum += f0 * f0 + f1 * f1;
        e[(long)base * 16 + d] = f2bf(q0);
        e[(long)(base + 256) * 16 + d] = f2bf(q1);
    }
    #pragma unroll
    for (int off = 32; off > 0; off >>= 1) lsum += __shfl_down(lsum, off, 64);
    if ((threadIdx.x & 63) == 0) sred[threadIdx.x >> 6] = lsum;
    __syncthreads();
    if (threadIdx.x == 0)
        atomicAdd(&acc[(blockIdx.x & 63) << 5],
                  sred[0] + sred[1] + sred[2] + sred[3]);
}

// ---------------- dec1 MFMA: e -> d1p [B,129,129,64] (interleaved) ----------
__global__ __launch_bounds__(256, 4) void dec1_k(const ushort_t* __restrict__ e,
        const ushort_t* __restrict__ wt, const float* __restrict__ bias,
        ushort_t* __restrict__ d1p) {
    const int L = xcd_chunk(blockIdx.y, gridDim.y);
    const int b = L >> 6, i = L & 63;
    const int tid = threadIdx.x;
    __shared__ __align__(16) ushort_t sE[2 * 66 * 24];  // [dh2][j66][ci16 pad24]
    uint4* z4 = (uint4*)sE;
    #pragma unroll
    for (int it = 0; it < 2; ++it) {
        int slot = it * 256 + tid;
        if (slot < 396) z4[slot] = (uint4){0, 0, 0, 0};
    }
    __syncthreads();
    {
        int dh = tid >> 7, rem = tid & 127, j = rem >> 1, ci8 = (rem & 1) * 8;
        if (i + dh < 64) {
            uint4 v = *(const uint4*)(e + ((long)((b * 64 + i + dh) * 64 + j)) * 16 + ci8);
            *(uint4*)&sE[(dh * 66 + j) * 24 + ci8] = v;
        }
    }
    __syncthreads();
    const int lane = tid & 63, wave = tid >> 6, q = lane >> 4, n16 = lane & 15;
    f32x4 acc[4][4];   // [class ph*2+pw][ntile]
    #pragma unroll
    for (int u = 0; u < 4; ++u) {
        float bz = bias[u * 16 + n16];
        #pragma unroll
        for (int c = 0; c < 4; ++c) acc[c][u] = (f32x4){bz, bz, bz, bz};
    }
    const int jl = wave * 16 + n16;
    #pragma unroll
    for (int t = 0; t < 9; ++t) {
        const int kh = t / 3, kw = t % 3;
        const int dh = (kh == 0) ? 1 : 0, dw = (kw == 0) ? 1 : 0;
        const int cls = ((kh != 1) ? 2 : 0) | ((kw != 1) ? 1 : 0);
        bf16x8 A = *(bf16x8*)&sE[(dh * 66 + jl + dw) * 24 + (q & 1) * 8];
        #pragma unroll
        for (int u = 0; u < 4; ++u) {
            bf16x8 B = *(const bf16x8*)(wt + 19456 + t * 2048 + (u * 16 + n16) * 32 + q * 8);
            acc[cls][u] = __builtin_amdgcn_mfma_f32_16x16x32_bf16(A, B, acc[cls][u], 0, 0, 0);
        }
    }
    #pragma unroll
    for (int ph = 0; ph < 2; ++ph)
        #pragma unroll
        for (int pw = 0; pw < 2; ++pw)
            #pragma unroll
            for (int r = 0; r < 4; ++r) {
                int oh = 2 * i + ph;
                int ow = 2 * (wave * 16 + q * 4 + r) + pw;
                uint2 pk;
                pk.x = pack2r(acc[ph * 2 + pw][0][r], acc[ph * 2 + pw][1][r]);
                pk.y = pack2r(acc[ph * 2 + pw][2][r], acc[ph * 2 + pw][3][r]);
                *(uint2*)(d1p + (size_t)b * 1065024 + ((long)oh * 129 + ow) * 64 + n16 * 4) = pk;
            }
}

// ---------------- dec23: fused convT(64->32,s2) + conv(32->3) + MSE ---------
// Block: output rows 4*i4..4*i4+3, cols j0..j0+127 (j0 = bx*128).
// Stage 1 (R19): CELL-OUTER, classes inner. Per cell: batch-load all 8
// A-frags [kc][dh][dw] (one vmcnt wait — all 9 taps reuse them), then per
// parity class batch-load its B-frags (4-16 in flight) and run the MFMA
// chain. Exposed load-waits per wave: ~126 (serialized) -> ~25 (batched).
// MFMA order per acc chain identical to R14/R16 (bitwise same numerics).
// Stage 2 (R16): kw=1 frags from sT + DPP row_ror for kw=0/2; border init.
__global__ __launch_bounds__(256, 3) void dec23_k(const ushort_t* __restrict__ d1p,
        const ushort_t* __restrict__ wt, const float* __restrict__ db2,
        const float* __restrict__ db3, const float* __restrict__ x,
        float* __restrict__ acc) {
    const int flat = blockIdx.y * 2 + blockIdx.x;
    const int L = xcd_chunk(flat, gridDim.y * 2);
    const int bx = L & 1, byl = L >> 1;
    const int b = byl >> 6, i4 = byl & 63;
    const int j0 = bx << 7;
    const int tid = threadIdx.x;
    const int lane = tid & 63, wave = tid >> 6, q = lane >> 4, n16 = lane & 15;

    __shared__ __align__(16) ushort_t sT[6 * 132 * 32];   // [R'6][c'132][ch32] 50688 B
    __shared__ float sred[4];

    // ---- targeted border init (interior is fully written by stage 1) ----
    {
        unsigned* sw = (unsigned*)sT;                 // row stride 2112 uints
        if (tid < 96) {
            int r6 = tid >> 4, w16 = tid & 15;
            int c = (bx == 0) ? 0 : 129;
            sw[r6 * 2112 + c * 16 + w16] = 0u;
        }
        if (i4 == 0)
            for (int i = tid; i < 2080; i += 256) sw[i] = 0u;
        if (i4 == 63)
            for (int i = tid; i < 2080; i += 256) sw[5 * 2112 + i] = 0u;
    }
    __syncthreads();

    // ---- stage 1: dec2 into sT (cell-outer, batched loads) ----
    const int bb0 = (j0 >> 1) - 1;
    const ushort_t* dbase = d1p + (size_t)b * 1065024;
    const int aidx = wave;
    const int a = 2 * i4 + aidx - 1;
    const bool doP0 = (aidx != 0);    // d2 row 2a+0 in tile?
    const bool doP1 = (aidx != 3);    // d2 row 2a+1 in tile?
    int r0 = ((unsigned)a <= 128u) ? a : 128;
    int r1 = ((unsigned)(a + 1) <= 128u) ? (a + 1) : 128;
    const ushort_t* rowp[2] = { dbase + (long)r0 * 8256, dbase + (long)r1 * 8256 };
    const float bz0 = db2[n16], bz1 = db2[16 + n16];

#define BL(B, T)                                                                    \
    _Pragma("unroll")                                                               \
    for (int kc = 0; kc < 2; ++kc)                                                  \
        _Pragma("unroll")                                                           \
        for (int u = 0; u < 2; ++u)                                                 \
            B[kc][u] = *(const bf16x8*)(wt + 37888 + (T) * 2048 + kc * 1024         \
                                        + (u * 16 + n16) * 32 + q * 8);
#define MAC(c0v, c1v, DH, DW, B)                                                    \
    c0v = __builtin_amdgcn_mfma_f32_16x16x32_bf16(A8[0][DH][DW], B[0][0], c0v, 0, 0, 0); \
    c1v = __builtin_amdgcn_mfma_f32_16x16x32_bf16(A8[0][DH][DW], B[0][1], c1v, 0, 0, 0); \
    c0v = __builtin_amdgcn_mfma_f32_16x16x32_bf16(A8[1][DH][DW], B[1][0], c0v, 0, 0, 0); \
    c1v = __builtin_amdgcn_mfma_f32_16x16x32_bf16(A8[1][DH][DW], B[1][1], c1v, 0, 0, 0);
#define EPI(cell, PH, PW, c0v, c1v)                                                 \
    {                                                                               \
        int R = 2 * a + (PH);                                                       \
        if ((unsigned)R < 256u) {                                                   \
            int Rp = R - 4 * i4 + 1;                                                \
            _Pragma("unroll")                                                       \
            for (int r = 0; r < 4; ++r) {                                           \
                int lq = (cell) * 16 + q * 4 + r;                                   \
                int cp = 2 * lq + (PW) - 1;                                         \
                int cg = 2 * (bb0 + lq) + (PW);                                     \
                if ((unsigned)cg < 256u && (unsigned)cp < 130u)                     \
                    *(unsigned*)&sT[Rp * 4224 + cp * 32 + n16 * 2] =                \
                        pack2r(c0v[r], c1v[r]);                                     \
            }                                                                       \
        }                                                                           \
    }
// taps by class (verified R14 mapping): cls0: t4(0,0); cls1: t3(0,1),t5(0,0);
// cls2: t1(1,0),t7(0,0); cls3: t0(1,1),t2(1,0),t6(0,1),t8(0,0)
#define CELL(cell)                                                                  \
    {                                                                               \
        int ca = bb0 + (cell) * 16 + n16;                                           \
        int o0 = (((unsigned)ca <= 128u) ? ca : 128) * 64;                          \
        int cbn = ca + 1;                                                           \
        int o1 = (((unsigned)cbn <= 128u) ? cbn : 128) * 64;                        \
        bf16x8 A8[2][2][2];   /* [kc][dh][dw] — batched, one wait */                \
        _Pragma("unroll")                                                           \
        for (int kc = 0; kc < 2; ++kc)                                              \
            _Pragma("unroll")                                                       \
            for (int dh = 0; dh < 2; ++dh) {                                        \
                A8[kc][dh][0] = *(const bf16x8*)(rowp[dh] + o0 + kc * 32 + q * 8);  \
                A8[kc][dh][1] = *(const bf16x8*)(rowp[dh] + o1 + kc * 32 + q * 8);  \
            }                                                                       \
        if (doP0) {                                                                 \
            {   bf16x8 Bt[2][2]; BL(Bt, 4)                                          \
                f32x4 c0 = (f32x4){bz0, bz0, bz0, bz0};                             \
                f32x4 c1 = (f32x4){bz1, bz1, bz1, bz1};                             \
                MAC(c0, c1, 0, 0, Bt)                                               \
                EPI(cell, 0, 0, c0, c1)                                             \
            }                                                                       \
            {   bf16x8 B3[2][2]; BL(B3, 3)                                          \
                bf16x8 B5[2][2]; BL(B5, 5)                                          \
                f32x4 c0 = (f32x4){bz0, bz0, bz0, bz0};                             \
                f32x4 c1 = (f32x4){bz1, bz1, bz1, bz1};                             \
                MAC(c0, c1, 0, 1, B3)                                               \
                MAC(c0, c1, 0, 0, B5)                                               \
                EPI(cell, 0, 1, c0, c1)                                             \
            }                                                                       \
        }                                                                           \
        if (doP1) {                                                                 \
            {   bf16x8 B1[2][2]; BL(B1, 1)                                          \
                bf16x8 B7[2][2]; BL(B7, 7)                                          \
                f32x4 c0 = (f32x4){bz0, bz0, bz0, bz0};                             \
                f32x4 c1 = (f32x4){bz1, bz1, bz1, bz1};                             \
                MAC(c0, c1, 1, 0, B1)                                               \
                MAC(c0, c1, 0, 0, B7)                                               \
                EPI(cell, 1, 0, c0, c1)                                             \
            }                                                                       \
            {   bf16x8 B0[2][2]; BL(B0, 0)                                          \
                bf16x8 B2[2][2]; BL(B2, 2)                                          \
                bf16x8 B6[2][2]; BL(B6, 6)                                          \
                bf16x8 B8[2][2]; BL(B8, 8)                                          \
                f32x4 c0 = (f32x4){bz0, bz0, bz0, bz0};                             \
                f32x4 c1 = (f32x4){bz1, bz1, bz1, bz1};                             \
                MAC(c0, c1, 1, 1, B0)                                               \
                MAC(c0, c1, 1, 0, B2)                                               \
                MAC(c0, c1, 0, 1, B6)                                               \
                MAC(c0, c1, 0, 0, B8)                                               \
                EPI(cell, 1, 1, c0, c1)                                             \
            }                                                                       \
        }                                                                           \
    }
    CELL(0) CELL(1) CELL(2) CELL(3) CELL(4)
#undef BL
#undef MAC
#undef EPI
#undef CELL
    __syncthreads();

    // ---- stage 2: dec3 conv + MSE (wave -> row oh, cols j0..j0+127) ----
    float bz3 = (n16 < 3) ? db3[n16] : 0.f;
    f32x4 a4[8];
    #pragma unroll
    for (int mf = 0; mf < 8; ++mf) a4[mf] = (f32x4){bz3, bz3, bz3, bz3};
    const int oh = 4 * i4 + wave;
    const bool is_l0 = (n16 == 0), is_l15 = (n16 == 15);
    #pragma unroll
    for (int kh = 0; kh < 3; ++kh) {
        const ushort_t* srow = &sT[(wave + kh) * 4224];
        bf16x8 Bk0 = *(const bf16x8*)(wt + 56320 + (kh * 3 + 0) * 512 + n16 * 32 + q * 8);
        bf16x8 Bk1 = *(const bf16x8*)(wt + 56320 + (kh * 3 + 1) * 512 + n16 * 32 + q * 8);
        bf16x8 Bk2 = *(const bf16x8*)(wt + 56320 + (kh * 3 + 2) * 512 + n16 * 32 + q * 8);
        // kw=1 fragments (c = m+1) + edge fragments
        bf16x8 G[8];
        #pragma unroll
        for (int mf = 0; mf < 8; ++mf)
            G[mf] = *(const bf16x8*)(srow + (mf * 16 + n16 + 1) * 32 + q * 8);
        bf16x8 E  = *(const bf16x8*)(srow + n16 * 32 + q * 8);          // lane0 -> c=0
        bf16x8 E2 = *(const bf16x8*)(srow + (114 + n16) * 32 + q * 8);  // lane15 -> c=129
        #pragma unroll
        for (int mf = 0; mf < 8; ++mf)
            a4[mf] = __builtin_amdgcn_mfma_f32_16x16x32_bf16(G[mf], Bk1, a4[mf], 0, 0, 0);
        // kw=0 (c = m): lane n takes lane n-1's G; lane0 patched from prev frag
        bf16x8 P = E;
        #pragma unroll
        for (int mf = 0; mf < 8; ++mf) {
            bf16x8 Qm; ROR_FRAG(Qm, G[mf], 0x121);      // ror:1 -> src[n-1]
            bf16x8 kw0 = is_l0 ? P : Qm;
            a4[mf] = __builtin_amdgcn_mfma_f32_16x16x32_bf16(kw0, Bk0, a4[mf], 0, 0, 0);
            P = Qm;
        }
        // kw=2 (c = m+2): lane n takes lane n+1's G; lane15 patched from next frag
        P = E2;
        #pragma unroll
        for (int mf = 7; mf >= 0; --mf) {
            bf16x8 Rm; ROR_FRAG(Rm, G[mf], 0x12F);      // ror:15 -> src[n+1]
            bf16x8 kw2 = is_l15 ? P : Rm;
            a4[mf] = __builtin_amdgcn_mfma_f32_16x16x32_bf16(kw2, Bk2, a4[mf], 0, 0, 0);
            P = Rm;
        }
    }
    float lsum = 0.f;
    if (n16 < 3) {
        const float* xrow = x + ((long)(b * 3 + n16) * 256 + oh) * 256 + j0;
        #pragma unroll
        for (int mf = 0; mf < 8; ++mf)
            #pragma unroll
            for (int r = 0; r < 4; ++r) {
                int ow = mf * 16 + q * 4 + r;
                float df = a4[mf][r] - xrow[ow];
                lsum += df * df;
            }
    }
    #pragma unroll
    for (int off = 32; off > 0; off >>= 1) lsum += __shfl_down(lsum, off, 64);
    if (lane == 0) sred[wave] = lsum;
    __syncthreads();
    if (tid == 0)
        atomicAdd(&acc[2048 + ((byl & 63) << 5)],
                  sred[0] + sred[1] + sred[2] + sred[3]);
}

__global__ void finalize_k(const float* __restrict__ acc, float* __restrict__ out) {
    int t = threadIdx.x;                 // 64 threads
    float v = acc[t << 5];
    float m = acc[2048 + (t << 5)];
    #pragma unroll
    for (int off = 32; off > 0; off >>= 1) {
        v += __shfl_down(v, off, 64);
        m += __shfl_down(m, off, 64);
    }
    if (t == 0) {
        float eq  = 1.25f * v / 4194304.f;     // 262144 px * 16 d
        float mse = m / 12582912.f;            // 64 * 3 * 256 * 256
        out[0] = eq;
        out[1] = mse;
        out[2] = mse;
    }
}

extern "C" void kernel_launch(void* const* d_in, const int* in_sizes, int n_in,
                              void* d_out, int out_size, void* d_ws, size_t ws_size,
                              hipStream_t stream) {
    (void)in_sizes; (void)n_in; (void)out_size;
    const float* x   = (const float*)d_in[0];
    const float* ew1 = (const float*)d_in[1];
    const float* eb1 = (const float*)d_in[2];
    const float* ew2 = (const float*)d_in[3];
    const float* eb2 = (const float*)d_in[4];
    const float* ew3 = (const float*)d_in[5];
    const float* eb3 = (const float*)d_in[6];
    const float* cb  = (const float*)d_in[7];
    const float* dw1 = (const float*)d_in[8];
    const float* db1 = (const float*)d_in[9];
    const float* dw2 = (const float*)d_in[10];
    const float* db2 = (const float*)d_in[11];
    const float* dw3 = (const float*)d_in[12];
    const float* db3 = (const float*)d_in[13];
    float* out = (float*)d_out;

    // workspace: acc 16384 B | wbuf 131072 B | e C*131072 | rgn C*2130048
    // need(C) = 147456 + C*2261120   (C=64 -> ~144.9 MB)
    int C = 64;
    while (C > 1 && (size_t)147456 + (size_t)C * 2261120UL > ws_size) C >>= 1;

    char* base = (char*)d_ws;
    float*    acc = (float*)base;                            // 4096 floats
    ushort_t* wt  = (ushort_t*)(base + 16384);
    float*    cn  = (float*)(base + 16384 + 121856);
    ushort_t* e   = (ushort_t*)(base + 147456);
    char*     rgn = base + 147456 + (size_t)C * 131072UL;
    ushort_t* a1  = (ushort_t*)rgn;
    ushort_t* a2  = (ushort_t*)(rgn + (size_t)C * 1048576UL);
    ushort_t* d1p = (ushort_t*)rgn;                          // reuse (a1/a2 dead)

    zero_k<<<16, 256, 0, stream>>>(acc);
    prep_k<<<240, 256, 0, stream>>>(ew1, ew2, dw1, dw2, dw3, cb, wt, cn);

    for (int b0 = 0; b0 < 64; b0 += C) {
        const float* xc = x + (size_t)b0 * 196608UL;
        conv1_k   <<<dim3(1, C * 128), 256, 0, stream>>>(xc,  wt, eb1, a1);
        conv2_k   <<<dim3(1, C * 64),  256, 0, stream>>>(a1,  wt, eb2, a2);
        conv3_vq_k<<<dim3(C * 8),      256, 0, stream>>>(a2,  ew3, eb3, cb, cn, e, acc);
        pad_k     <<<dim3(C),          256, 0, stream>>>(d1p);
        dec1_k    <<<dim3(1, C * 64),  256, 0, stream>>>(e,   wt, db1, d1p);
        dec23_k   <<<dim3(2, C * 64),  256, 0, stream>>>(d1p, wt, db2, db3, xc, acc);
    }
    finalize_k<<<1, 64, 0, stream>>>(acc, out);
}

// Round 9
// 639.649 us; speedup vs baseline: 1.2225x; 1.2225x over previous
//
#include <hip/hip_runtime.h>
#include <hip/hip_bf16.h>

// VQ-VAE forward — NHWC bf16 intermediates, MFMA (16x16x32 bf16) for all convs.
// Outputs: [1.25*vq_mse, recon_mse, recon_mse]
//
// MFMA lane layouts (gfx950, HW-verified per guide):
//   A: m = lane&15, k = (lane>>4)*8 + j     (8 bf16 / lane)
//   B: n = lane&15, k = (lane>>4)*8 + j
//   D: n = lane&15, m = (lane>>4)*4 + reg   (4 f32 / lane)
//
// CHANNEL-INTERLEAVED storage: a producer with U=Cc/16 tiles stores tile u,
// column n16 (logical co = u*16+n16) at memory channel m = n16*U+u; consumers
// permute ci in weight prep: logical l(m) = (m%U)*16 + m/U.
//
// dec2+dec3 FUSED (dec23_k). R13: 1 atomic/block (580->409). R14: class-
// sequential stage 1 (409->323). R15: XCD swizzle (FETCH -55%, flat).
// R16: DPP kw-dedup + border init (319, best). R17/R18: occupancy probes
// (null). R19: cell-outer (455, REGRESSION — B-redundancy 36->180 loads).
// R19 p.m. quantified the real resource: ~320 cy per load INSTRUCTION
// (independent of cache level); per-CU throughput ~1 load-instr/47cy
// (~16 lines/instr at 0.34 lines/cy L1/TA). Time tracks load-instr count
// across ALL rounds.
// R20: revert to R16 structure + hoist (dh,dw)=(0,0) A-fragments (used by
// taps 4,5,7,8 — one per class) into A00[2][5] regs once per wave:
// A-loads 90->60, total 126->96 (-24%). +40 VGPR (84->~125), under the
// 170 cap at launch_bounds(256,3) — no spill (R17 lesson; WRITE_SIZE canary).
//
// d1p [B][129][129][64]: interior (0,0)..(127,127); pad row/col 128 = 0.

typedef __attribute__((ext_vector_type(8))) short bf16x8;
typedef __attribute__((ext_vector_type(4))) float f32x4;
typedef __attribute__((ext_vector_type(4))) int i32x4;
typedef unsigned short ushort_t;

__device__ __forceinline__ ushort_t f2bf(float v) {
    __hip_bfloat16 h = __float2bfloat16(v);
    return *(ushort_t*)&h;
}
__device__ __forceinline__ float bf2f(ushort_t u) {
    __hip_bfloat16 h = *(__hip_bfloat16*)&u;
    return __bfloat162float(h);
}
__device__ __forceinline__ unsigned pack2r(float a, float b) {   // relu+pack
    return (unsigned)f2bf(fmaxf(a, 0.f)) | ((unsigned)f2bf(fmaxf(b, 0.f)) << 16);
}
// XCD-chunked bijective remap (requires nwg%8==0).
__device__ __forceinline__ int xcd_chunk(int flat, int nwg) {
    return (flat & 7) * (nwg >> 3) + (flat >> 3);
}
// DPP row-rotate of a 16B fragment within each 16-lane row.
// row_ror:N -> dst[n] = src[(n-N) mod 16].  0x121 = ror:1, 0x12F = ror:15.
#define ROR_FRAG(dst, src, CTRL)                                        \
    {                                                                   \
        i32x4 _a = __builtin_bit_cast(i32x4, src), _r;                  \
        _r[0] = __builtin_amdgcn_mov_dpp(_a[0], CTRL, 0xF, 0xF, false); \
        _r[1] = __builtin_amdgcn_mov_dpp(_a[1], CTRL, 0xF, 0xF, false); \
        _r[2] = __builtin_amdgcn_mov_dpp(_a[2], CTRL, 0xF, 0xF, false); \
        _r[3] = __builtin_amdgcn_mov_dpp(_a[3], CTRL, 0xF, 0xF, false); \
        dst = __builtin_bit_cast(bf16x8, _r);                           \
    }

// Accumulator layout (fp32, 4096 floats = 16 KB at workspace base):
//   vq  partials: acc[slot*32],        slot = 0..63   (128 B apart)
//   mse partials: acc[2048 + slot*32], slot = 0..63
//
// Transformed-weight layout in wbuf (elements of bf16, at base+16384):
//   W1T  @ 0      [co32][k32]            (k=ci*9+kh*3+kw, pad 27->32)
//   W2T  @ 1024   [t9][co64][ci32]       (ci permuted: l2(ci))
//   WD1  @ 19456  [t9][co64][k32]        (k<16 = ci natural, else 0)
//   WD2  @ 37888  [t9][kc2][co32][ci32]  (ci permuted: l4(kc*32+ci))
//   WD3  @ 56320  [t9][co16][ci32]       (taps FLIPPED: src 8-t; ci perm l2; co>=3 -> 0)
//   cn (fp32, 512) @ byte offset 121856 within wbuf

__global__ void zero_k(float* __restrict__ acc) {
    acc[blockIdx.x * 256 + threadIdx.x] = 0.f;
}

__global__ __launch_bounds__(256) void prep_k(
        const float* __restrict__ ew1, const float* __restrict__ ew2,
        const float* __restrict__ dw1, const float* __restrict__ dw2,
        const float* __restrict__ dw3, const float* __restrict__ cb,
        ushort_t* __restrict__ wt, float* __restrict__ cn) {
    int idx = blockIdx.x * 256 + threadIdx.x;
    if (idx < 1024) {
        int co = idx >> 5, k = idx & 31;
        wt[idx] = (k < 27) ? f2bf(ew1[co * 27 + k]) : (ushort_t)0;
    } else if (idx < 19456) {
        int i = idx - 1024;
        int t = i >> 11, co = (i >> 5) & 63, ci = i & 31;
        int lci = ((ci & 1) << 4) | (ci >> 1);                 // l2 (conv1 U=2)
        wt[idx] = f2bf(ew2[co * 288 + lci * 9 + t]);
    } else if (idx < 37888) {
        int i = idx - 19456;
        int t = i >> 11, co = (i >> 5) & 63, k = i & 31;
        wt[idx] = (k < 16) ? f2bf(dw1[k * 576 + co * 9 + t]) : (ushort_t)0;
    } else if (idx < 56320) {
        int i = idx - 37888;
        int t = i >> 11, kc = (i >> 10) & 1, co = (i >> 5) & 31, ci = i & 31;
        int m = kc * 32 + ci;
        int lci = ((m & 3) << 4) | (m >> 2);                   // l4 (dec1 U=4)
        wt[idx] = f2bf(dw2[lci * 288 + co * 9 + t]);
    } else if (idx < 60928) {
        int i = idx - 56320;
        int t = i >> 9, co = (i >> 5) & 15, ci = i & 31;
        int lci = ((ci & 1) << 4) | (ci >> 1);                 // l2 (dec2 U=2)
        wt[idx] = (co < 3) ? f2bf(dw3[lci * 27 + co * 9 + (8 - t)]) : (ushort_t)0;
    } else if (idx < 61440) {
        int k = idx - 60928;
        float s = 0.f;
        #pragma unroll
        for (int d = 0; d < 16; ++d) { float v = cb[k * 16 + d]; s += v * v; }
        cn[k] = s;
    }
}

// ---------------- zero the pad borders of d1p (one block per image) ---------
__global__ __launch_bounds__(256) void pad_k(ushort_t* __restrict__ d1p) {
    const int img = blockIdx.x, tid = threadIdx.x;
    const uint4 z = (uint4){0, 0, 0, 0};
    uint4* b1 = (uint4*)(d1p + (size_t)img * 1065024);   // 129*129*64 elems
    for (int i = tid; i < 1032; i += 256) b1[132096 + i] = z;   // row 128
    for (int i = tid; i < 1024; i += 256) {                     // col 128
        int r = i >> 3, u = i & 7;
        b1[(r * 129 + 128) * 8 + u] = z;
    }
}

// ---------------- conv1 MFMA: x NCHW fp32 -> a1 [B,128,128,32] (interleaved)
__global__ __launch_bounds__(256, 4) void conv1_k(const float* __restrict__ x,
        const ushort_t* __restrict__ wt, const float* __restrict__ bias,
        ushort_t* __restrict__ a1) {
    const int L = xcd_chunk(blockIdx.y, gridDim.y);
    const int b = L >> 7, oh = L & 127;
    const int tid = threadIdx.x;
    __shared__ __align__(16) ushort_t sX[9 * 264];   // [ci*3+kh][iw+1 (258 used)]
    __shared__ int sOff[32];
    for (int i = tid; i < 9 * 264 / 2; i += 256) ((unsigned*)sX)[i] = 0u;
    if (tid < 32) {
        int k = tid, off = 0;
        if (k < 27) { int ci = k / 9, r9 = k % 9, kh = r9 / 3, kw = r9 % 3;
                      off = (ci * 3 + kh) * 264 + kw; }
        sOff[tid] = off;
    }
    __syncthreads();
    #pragma unroll
    for (int it = 0; it < 9; ++it) {
        int slot = it * 256 + tid;                  // 2304 = 3ci * 3kh * 256iw
        int ci = slot / 768, r = slot % 768, kh = r >> 8, iw = r & 255;
        int ih = 2 * oh + kh - 1;
        float v = ((unsigned)ih < 256u) ? x[(long)(b * 3 + ci) * 65536 + ih * 256 + iw] : 0.f;
        sX[(ci * 3 + kh) * 264 + iw + 1] = f2bf(v);
    }
    __syncthreads();
    const int lane = tid & 63, wave = tid >> 6, q = lane >> 4, n16 = lane & 15;
    bf16x8 Bw[2];
    #pragma unroll
    for (int u = 0; u < 2; ++u)
        Bw[u] = *(const bf16x8*)(wt + (u * 16 + n16) * 32 + q * 8);
    f32x4 acc[2][2];
    #pragma unroll
    for (int u = 0; u < 2; ++u) {
        float bz = bias[u * 16 + n16];
        acc[0][u] = (f32x4){bz, bz, bz, bz};
        acc[1][u] = (f32x4){bz, bz, bz, bz};
    }
    #pragma unroll
    for (int mf = 0; mf < 2; ++mf) {
        const int m2 = 2 * (wave * 32 + mf * 16 + n16);
        ushort_t av[8];
        #pragma unroll
        for (int j = 0; j < 8; ++j) {
            int k = q * 8 + j;
            av[j] = (k < 27) ? sX[sOff[k] + m2] : (ushort_t)0;
        }
        bf16x8 A = *(bf16x8*)av;
        #pragma unroll
        for (int u = 0; u < 2; ++u)
            acc[mf][u] = __builtin_amdgcn_mfma_f32_16x16x32_bf16(A, Bw[u], acc[mf][u], 0, 0, 0);
    }
    #pragma unroll
    for (int mf = 0; mf < 2; ++mf)
        #pragma unroll
        for (int r = 0; r < 4; ++r) {
            int ow = wave * 32 + mf * 16 + q * 4 + r;
            *(unsigned*)(a1 + ((long)(b * 128 + oh) * 128 + ow) * 32 + n16 * 2) =
                pack2r(acc[mf][0][r], acc[mf][1][r]);
        }
}

// ---------------- conv2 MFMA: a1 -> a2 [B,64,64,64] (interleaved) -----------
__global__ __launch_bounds__(256, 4) void conv2_k(const ushort_t* __restrict__ a1,
        const ushort_t* __restrict__ wt, const float* __restrict__ bias,
        ushort_t* __restrict__ a2) {
    const int L = xcd_chunk(blockIdx.y, gridDim.y);
    const int b = L >> 6, oh = L & 63;
    const int tid = threadIdx.x;
    // parity-split: [kh3][p2][c66][ci32 pad40]
    __shared__ __align__(16) ushort_t sA[3 * 2 * 66 * 40];
    uint4* z4 = (uint4*)sA;
    #pragma unroll
    for (int it = 0; it < 8; ++it) {
        int slot = it * 256 + tid;
        if (slot < 1980) z4[slot] = (uint4){0, 0, 0, 0};
    }
    __syncthreads();
    #pragma unroll
    for (int it = 0; it < 6; ++it) {
        int slot = it * 256 + tid;                    // 1536 = 3kh*128iw*4
        if (slot < 1536) {
            int kh = slot >> 9, rem = slot & 511, iw = rem >> 2, ci8 = (rem & 3) << 3;
            int ih = 2 * oh + kh - 1;
            if ((unsigned)ih < 128u) {
                uint4 v = *(const uint4*)(a1 + ((long)(b * 128 + ih) * 128 + iw) * 32 + ci8);
                int idx = iw + 2, p = idx & 1, c = idx >> 1;
                *(uint4*)&sA[((kh * 2 + p) * 66 + c) * 40 + ci8] = v;
            }
        }
    }
    __syncthreads();
    const int lane = tid & 63, wave = tid >> 6, q = lane >> 4, n16 = lane & 15;
    f32x4 acc[4];
    #pragma unroll
    for (int u = 0; u < 4; ++u) {
        float bz = bias[u * 16 + n16];
        acc[u] = (f32x4){bz, bz, bz, bz};
    }
    const int ow = wave * 16 + n16;   // A row (m)
    #pragma unroll
    for (int t = 0; t < 9; ++t) {
        const int kh = t / 3, kw = t % 3;
        const int p = (kw == 1) ? 0 : 1;
        const int c = (kw == 0) ? ow : ow + 1;
        bf16x8 A = *(bf16x8*)&sA[((kh * 2 + p) * 66 + c) * 40 + q * 8];
        #pragma unroll
        for (int u = 0; u < 4; ++u) {
            bf16x8 B = *(const bf16x8*)(wt + 1024 + t * 2048 + (u * 16 + n16) * 32 + q * 8);
            acc[u] = __builtin_amdgcn_mfma_f32_16x16x32_bf16(A, B, acc[u], 0, 0, 0);
        }
    }
    #pragma unroll
    for (int r = 0; r < 4; ++r) {
        int owo = wave * 16 + q * 4 + r;
        uint2 pk;
        pk.x = pack2r(acc[0][r], acc[1][r]);
        pk.y = pack2r(acc[2][r], acc[3][r]);
        *(uint2*)(a2 + ((long)(b * 64 + oh) * 64 + owo) * 64 + n16 * 4) = pk;
    }
}

// ---------------- conv3 (1x1) + VQ + loss, 2 px/thread ----------------------
__global__ __launch_bounds__(256) void conv3_vq_k(const ushort_t* __restrict__ a2,
        const float* __restrict__ w3, const float* __restrict__ b3,
        const float* __restrict__ cb, const float* __restrict__ cn,
        ushort_t* __restrict__ e, float* __restrict__ acc) {
    const int base = blockIdx.x * 512 + threadIdx.x;   // px0 = base, px1 = base+256
    __shared__ float sred[4];
    float z[2][16];
    #pragma unroll
    for (int p = 0; p < 2; ++p)
        #pragma unroll
        for (int d = 0; d < 16; ++d) z[p][d] = b3[d];
    #pragma unroll
    for (int p = 0; p < 2; ++p) {
        const ushort_t* arow = a2 + (long)(base + p * 256) * 64;
        #pragma unroll
        for (int c8 = 0; c8 < 8; ++c8) {
            uint4 raw = *(const uint4*)(arow + c8 * 8);
            ushort_t us[8];
            *(uint4*)us = raw;
            #pragma unroll
            for (int j = 0; j < 8; ++j) {
                int m = c8 * 8 + j;
                int lci = ((m & 3) << 4) | (m >> 2);          // l4
                float a = bf2f(us[j]);
                #pragma unroll
                for (int d = 0; d < 16; ++d)
                    z[p][d] = fmaf(a, w3[d * 64 + lci], z[p][d]);
            }
        }
    }
    const float4* cb4 = (const float4*)cb;
    float best0 = 1e30f, best1 = 1e30f; int bi0 = 0, bi1 = 0;
    for (int k = 0; k < 512; ++k) {
        float4 c0 = cb4[k * 4 + 0], c1 = cb4[k * 4 + 1];
        float4 c2 = cb4[k * 4 + 2], c3 = cb4[k * 4 + 3];
        float nk = cn[k];
        float d0 = z[0][0]*c0.x + z[0][1]*c0.y + z[0][2]*c0.z + z[0][3]*c0.w
                 + z[0][4]*c1.x + z[0][5]*c1.y + z[0][6]*c1.z + z[0][7]*c1.w
                 + z[0][8]*c2.x + z[0][9]*c2.y + z[0][10]*c2.z + z[0][11]*c2.w
                 + z[0][12]*c3.x + z[0][13]*c3.y + z[0][14]*c3.z + z[0][15]*c3.w;
        float d1 = z[1][0]*c0.x + z[1][1]*c0.y + z[1][2]*c0.z + z[1][3]*c0.w
                 + z[1][4]*c1.x + z[1][5]*c1.y + z[1][6]*c1.z + z[1][7]*c1.w
                 + z[1][8]*c2.x + z[1][9]*c2.y + z[1][10]*c2.z + z[1][11]*c2.w
                 + z[1][12]*c3.x + z[1][13]*c3.y + z[1][14]*c3.z + z[1][15]*c3.w;
        float dist0 = nk - 2.f * d0, dist1 = nk - 2.f * d1;
        if (dist0 < best0) { best0 = dist0; bi0 = k; }
        if (dist1 < best1) { best1 = dist1; bi1 = k; }
    }
    float lsum = 0.f;
    #pragma unroll
    for (int d = 0; d < 16; ++d) {
        float q0 = cb[bi0 * 16 + d], q1 = cb[bi1 * 16 + d];
        float f0 = q0 - z[0][d], f1 = q1 - z[1][d];
        lsum += f0 * f0 + f1 * f1;
        e[(long)base * 16 + d] = f2bf(q0);
        e[(long)(base + 256) * 16 + d] = f2bf(q1);
    }
    #pragma unroll
    for (int off = 32; off > 0; off >>= 1) lsum += __shfl_down(lsum, off, 64);
    if ((threadIdx.x & 63) == 0) sred[threadIdx.x >> 6] = lsum;
    __syncthreads();
    if (threadIdx.x == 0)
        atomicAdd(&acc[(blockIdx.x & 63) << 5],
                  sred[0] + sred[1] + sred[2] + sred[3]);
}

// ---------------- dec1 MFMA: e -> d1p [B,129,129,64] (interleaved) ----------
__global__ __launch_bounds__(256, 4) void dec1_k(const ushort_t* __restrict__ e,
        const ushort_t* __restrict__ wt, const float* __restrict__ bias,
        ushort_t* __restrict__ d1p) {
    const int L = xcd_chunk(blockIdx.y, gridDim.y);
    const int b = L >> 6, i = L & 63;
    const int tid = threadIdx.x;
    __shared__ __align__(16) ushort_t sE[2 * 66 * 24];  // [dh2][j66][ci16 pad24]
    uint4* z4 = (uint4*)sE;
    #pragma unroll
    for (int it = 0; it < 2; ++it) {
        int slot = it * 256 + tid;
        if (slot < 396) z4[slot] = (uint4){0, 0, 0, 0};
    }
    __syncthreads();
    {
        int dh = tid >> 7, rem = tid & 127, j = rem >> 1, ci8 = (rem & 1) * 8;
        if (i + dh < 64) {
            uint4 v = *(const uint4*)(e + ((long)((b * 64 + i + dh) * 64 + j)) * 16 + ci8);
            *(uint4*)&sE[(dh * 66 + j) * 24 + ci8] = v;
        }
    }
    __syncthreads();
    const int lane = tid & 63, wave = tid >> 6, q = lane >> 4, n16 = lane & 15;
    f32x4 acc[4][4];   // [class ph*2+pw][ntile]
    #pragma unroll
    for (int u = 0; u < 4; ++u) {
        float bz = bias[u * 16 + n16];
        #pragma unroll
        for (int c = 0; c < 4; ++c) acc[c][u] = (f32x4){bz, bz, bz, bz};
    }
    const int jl = wave * 16 + n16;
    #pragma unroll
    for (int t = 0; t < 9; ++t) {
        const int kh = t / 3, kw = t % 3;
        const int dh = (kh == 0) ? 1 : 0, dw = (kw == 0) ? 1 : 0;
        const int cls = ((kh != 1) ? 2 : 0) | ((kw != 1) ? 1 : 0);
        bf16x8 A = *(bf16x8*)&sE[(dh * 66 + jl + dw) * 24 + (q & 1) * 8];
        #pragma unroll
        for (int u = 0; u < 4; ++u) {
            bf16x8 B = *(const bf16x8*)(wt + 19456 + t * 2048 + (u * 16 + n16) * 32 + q * 8);
            acc[cls][u] = __builtin_amdgcn_mfma_f32_16x16x32_bf16(A, B, acc[cls][u], 0, 0, 0);
        }
    }
    #pragma unroll
    for (int ph = 0; ph < 2; ++ph)
        #pragma unroll
        for (int pw = 0; pw < 2; ++pw)
            #pragma unroll
            for (int r = 0; r < 4; ++r) {
                int oh = 2 * i + ph;
                int ow = 2 * (wave * 16 + q * 4 + r) + pw;
                uint2 pk;
                pk.x = pack2r(acc[ph * 2 + pw][0][r], acc[ph * 2 + pw][1][r]);
                pk.y = pack2r(acc[ph * 2 + pw][2][r], acc[ph * 2 + pw][3][r]);
                *(uint2*)(d1p + (size_t)b * 1065024 + ((long)oh * 129 + ow) * 64 + n16 * 4) = pk;
            }
}

// ---------------- dec23: fused convT(64->32,s2) + conv(32->3) + MSE ---------
// Block: output rows 4*i4..4*i4+3, cols j0..j0+127 (j0 = bx*128).
// Stage 1 (R14+R20): wave = one a-row, 5 cells, class-sequential acc reuse.
// R20: (dh,dw)=(0,0) A-fragments hoisted into A00[2][5] once per wave —
// shared by taps 4,5,7,8 (one per class). A-loads 90->60.
// Stage 2 (R16): kw=1 frags from sT + DPP row_ror for kw=0/2; border init.
__global__ __launch_bounds__(256, 3) void dec23_k(const ushort_t* __restrict__ d1p,
        const ushort_t* __restrict__ wt, const float* __restrict__ db2,
        const float* __restrict__ db3, const float* __restrict__ x,
        float* __restrict__ acc) {
    const int flat = blockIdx.y * 2 + blockIdx.x;
    const int L = xcd_chunk(flat, gridDim.y * 2);
    const int bx = L & 1, byl = L >> 1;
    const int b = byl >> 6, i4 = byl & 63;
    const int j0 = bx << 7;
    const int tid = threadIdx.x;
    const int lane = tid & 63, wave = tid >> 6, q = lane >> 4, n16 = lane & 15;

    __shared__ __align__(16) ushort_t sT[6 * 132 * 32];   // [R'6][c'132][ch32] 50688 B
    __shared__ float sred[4];

    // ---- targeted border init (interior is fully written by stage 1) ----
    // unwritten-but-read: col 0 (bx=0), col 129 (bx=1), row 0 (i4=0), row 5 (i4=63)
    {
        unsigned* sw = (unsigned*)sT;
        if (tid < 96) {
            int r6 = tid >> 4, w16 = tid & 15;
            int c = (bx == 0) ? 0 : 129;
            sw[r6 * 2112 + c * 16 + w16] = 0u;
        }
        if (i4 == 0)
            for (int i = tid; i < 2080; i += 256) sw[i] = 0u;
        if (i4 == 63)
            for (int i = tid; i < 2080; i += 256) sw[5 * 2112 + i] = 0u;
    }
    __syncthreads();

    // ---- stage 1: dec2 into sT (class-sequential, one a-row per wave) ----
    const int bb0 = (j0 >> 1) - 1;
    const ushort_t* dbase = d1p + (size_t)b * 1065024;
    const int aidx = wave;
    const int a = 2 * i4 + aidx - 1;
    const bool doP0 = (aidx != 0);    // d2 row 2a+0 in tile?
    const bool doP1 = (aidx != 3);    // d2 row 2a+1 in tile?
    // row pointers, OOB rows -> zero pad row 128
    int r0 = a, r1 = a + 1;
    r0 = ((unsigned)r0 <= 128u) ? r0 : 128;
    r1 = ((unsigned)r1 <= 128u) ? r1 : 128;
    const ushort_t* rowp0 = dbase + (long)r0 * 8256;   // 129*64
    const ushort_t* rowp1 = dbase + (long)r1 * 8256;
    // per-lane col element-offsets, OOB cols -> zero pad col 128
    int colo[5][2];
    #pragma unroll
    for (int cell = 0; cell < 5; ++cell)
        #pragma unroll
        for (int dw = 0; dw < 2; ++dw) {
            int col = bb0 + cell * 16 + n16 + dw;
            colo[cell][dw] = (((unsigned)col <= 128u) ? col : 128) * 64;
        }
    const float bz0 = db2[n16], bz1 = db2[16 + n16];
    f32x4 a5[2][5];                                    // [u][cell], per class

    // R20: hoisted (dh,dw)=(0,0) fragments — used by taps 4,5,7,8
    bf16x8 A00[2][5];                                  // [kc][cell]
    #pragma unroll
    for (int kc = 0; kc < 2; ++kc)
        #pragma unroll
        for (int cell = 0; cell < 5; ++cell)
            A00[kc][cell] = *(const bf16x8*)(rowp0 + colo[cell][0] + kc * 32 + q * 8);

#define INIT5()                                                                     \
    _Pragma("unroll")                                                               \
    for (int cell = 0; cell < 5; ++cell) {                                          \
        a5[0][cell] = (f32x4){bz0, bz0, bz0, bz0};                                  \
        a5[1][cell] = (f32x4){bz1, bz1, bz1, bz1};                                  \
    }
#define TAP5(T, DH, DW)                                                             \
    {                                                                               \
        const ushort_t* wb = wt + 37888 + (T) * 2048;                               \
        const ushort_t* rp = (DH) ? rowp1 : rowp0;                                  \
        _Pragma("unroll")                                                           \
        for (int kc = 0; kc < 2; ++kc) {                                            \
            bf16x8 B0 = *(const bf16x8*)(wb + kc * 1024 + n16 * 32 + q * 8);        \
            bf16x8 B1 = *(const bf16x8*)(wb + kc * 1024 + (16 + n16) * 32 + q * 8); \
            _Pragma("unroll")                                                       \
            for (int cell = 0; cell < 5; ++cell) {                                  \
                bf16x8 Av = *(const bf16x8*)(rp + colo[cell][DW] + kc * 32 + q * 8);\
                a5[0][cell] = __builtin_amdgcn_mfma_f32_16x16x32_bf16(              \
                    Av, B0, a5[0][cell], 0, 0, 0);                                  \
                a5[1][cell] = __builtin_amdgcn_mfma_f32_16x16x32_bf16(              \
                    Av, B1, a5[1][cell], 0, 0, 0);                                  \
            }                                                                       \
        }                                                                           \
    }
#define TAP5H(T)                                                                    \
    {                                                                               \
        const ushort_t* wb = wt + 37888 + (T) * 2048;                               \
        _Pragma("unroll")                                                           \
        for (int kc = 0; kc < 2; ++kc) {                                            \
            bf16x8 B0 = *(const bf16x8*)(wb + kc * 1024 + n16 * 32 + q * 8);        \
            bf16x8 B1 = *(const bf16x8*)(wb + kc * 1024 + (16 + n16) * 32 + q * 8); \
            _Pragma("unroll")                                                       \
            for (int cell = 0; cell < 5; ++cell) {                                  \
                a5[0][cell] = __builtin_amdgcn_mfma_f32_16x16x32_bf16(              \
                    A00[kc][cell], B0, a5[0][cell], 0, 0, 0);                       \
                a5[1][cell] = __builtin_amdgcn_mfma_f32_16x16x32_bf16(              \
                    A00[kc][cell], B1, a5[1][cell], 0, 0, 0);                       \
            }                                                                       \
        }                                                                           \
    }
#define EPI5(PH, PW)                                                                \
    {                                                                               \
        int R = 2 * a + (PH);                                                       \
        if ((unsigned)R < 256u) {                                                   \
            int Rp = R - 4 * i4 + 1;                                                \
            _Pragma("unroll")                                                       \
            for (int cell = 0; cell < 5; ++cell)                                    \
                _Pragma("unroll")                                                   \
                for (int r = 0; r < 4; ++r) {                                       \
                    int lq = cell * 16 + q * 4 + r;                                 \
                    int cp = 2 * lq + (PW) - 1;                                     \
                    int cg = 2 * (bb0 + lq) + (PW);                                 \
                    if ((unsigned)cg < 256u && (unsigned)cp < 130u)                 \
                        *(unsigned*)&sT[Rp * 4224 + cp * 32 + n16 * 2] =            \
                            pack2r(a5[0][cell][r], a5[1][cell][r]);                 \
                }                                                                   \
        }                                                                           \
    }
    // taps by class: cls = (kh!=1)*2 | (kw!=1); dh=(kh==0), dw=(kw==0)
    // (0,0)-taps (4,5,7,8) use hoisted A00 — one per class.
    if (doP0) {
        INIT5(); TAP5H(4); EPI5(0, 0);                             // cls0: (1,1)
        INIT5(); TAP5(3, 0, 1); TAP5H(5); EPI5(0, 1);              // cls1: (1,0),(1,2)
    }
    if (doP1) {
        INIT5(); TAP5(1, 1, 0); TAP5H(7); EPI5(1, 0);              // cls2: (0,1),(2,1)
        INIT5(); TAP5(0, 1, 1); TAP5(2, 1, 0); TAP5(6, 0, 1); TAP5H(8);
        EPI5(1, 1);                                                // cls3: corners
    }
#undef INIT5
#undef TAP5
#undef TAP5H
#undef EPI5
    __syncthreads();

    // ---- stage 2: dec3 conv + MSE (wave -> row oh, cols j0..j0+127) ----
    float bz3 = (n16 < 3) ? db3[n16] : 0.f;
    f32x4 a4[8];
    #pragma unroll
    for (int mf = 0; mf < 8; ++mf) a4[mf] = (f32x4){bz3, bz3, bz3, bz3};
    const int oh = 4 * i4 + wave;
    const bool is_l0 = (n16 == 0), is_l15 = (n16 == 15);
    #pragma unroll
    for (int kh = 0; kh < 3; ++kh) {
        const ushort_t* srow = &sT[(wave + kh) * 4224];
        bf16x8 Bk0 = *(const bf16x8*)(wt + 56320 + (kh * 3 + 0) * 512 + n16 * 32 + q * 8);
        bf16x8 Bk1 = *(const bf16x8*)(wt + 56320 + (kh * 3 + 1) * 512 + n16 * 32 + q * 8);
        bf16x8 Bk2 = *(const bf16x8*)(wt + 56320 + (kh * 3 + 2) * 512 + n16 * 32 + q * 8);
        // kw=1 fragments (c = m+1) + edge fragments
        bf16x8 G[8];
        #pragma unroll
        for (int mf = 0; mf < 8; ++mf)
            G[mf] = *(const bf16x8*)(srow + (mf * 16 + n16 + 1) * 32 + q * 8);
        bf16x8 E  = *(const bf16x8*)(srow + n16 * 32 + q * 8);          // lane0 -> c=0
        bf16x8 E2 = *(const bf16x8*)(srow + (114 + n16) * 32 + q * 8);  // lane15 -> c=129
        #pragma unroll
        for (int mf = 0; mf < 8; ++mf)
            a4[mf] = __builtin_amdgcn_mfma_f32_16x16x32_bf16(G[mf], Bk1, a4[mf], 0, 0, 0);
        // kw=0 (c = m): lane n takes lane n-1's G; lane0 patched from prev frag
        bf16x8 P = E;
        #pragma unroll
        for (int mf = 0; mf < 8; ++mf) {
            bf16x8 Qm; ROR_FRAG(Qm, G[mf], 0x121);      // ror:1 -> src[n-1]
            bf16x8 kw0 = is_l0 ? P : Qm;
            a4[mf] = __builtin_amdgcn_mfma_f32_16x16x32_bf16(kw0, Bk0, a4[mf], 0, 0, 0);
            P = Qm;
        }
        // kw=2 (c = m+2): lane n takes lane n+1's G; lane15 patched from next frag
        P = E2;
        #pragma unroll
        for (int mf = 7; mf >= 0; --mf) {
            bf16x8 Rm; ROR_FRAG(Rm, G[mf], 0x12F);      // ror:15 -> src[n+1]
            bf16x8 kw2 = is_l15 ? P : Rm;
            a4[mf] = __builtin_amdgcn_mfma_f32_16x16x32_bf16(kw2, Bk2, a4[mf], 0, 0, 0);
            P = Rm;
        }
    }
    float lsum = 0.f;
    if (n16 < 3) {
        const float* xrow = x + ((long)(b * 3 + n16) * 256 + oh) * 256 + j0;
        #pragma unroll
        for (int mf = 0; mf < 8; ++mf)
            #pragma unroll
            for (int r = 0; r < 4; ++r) {
                int ow = mf * 16 + q * 4 + r;
                float df = a4[mf][r] - xrow[ow];
                lsum += df * df;
            }
    }
    #pragma unroll
    for (int off = 32; off > 0; off >>= 1) lsum += __shfl_down(lsum, off, 64);
    if (lane == 0) sred[wave] = lsum;
    __syncthreads();
    if (tid == 0)
        atomicAdd(&acc[2048 + ((byl & 63) << 5)],
                  sred[0] + sred[1] + sred[2] + sred[3]);
}

__global__ void finalize_k(const float* __restrict__ acc, float* __restrict__ out) {
    int t = threadIdx.x;                 // 64 threads
    float v = acc[t << 5];
    float m = acc[2048 + (t << 5)];
    #pragma unroll
    for (int off = 32; off > 0; off >>= 1) {
        v += __shfl_down(v, off, 64);
        m += __shfl_down(m, off, 64);
    }
    if (t == 0) {
        float eq  = 1.25f * v / 4194304.f;     // 262144 px * 16 d
        float mse = m / 12582912.f;            // 64 * 3 * 256 * 256
        out[0] = eq;
        out[1] = mse;
        out[2] = mse;
    }
}

extern "C" void kernel_launch(void* const* d_in, const int* in_sizes, int n_in,
                              void* d_out, int out_size, void* d_ws, size_t ws_size,
                              hipStream_t stream) {
    (void)in_sizes; (void)n_in; (void)out_size;
    const float* x   = (const float*)d_in[0];
    const float* ew1 = (const float*)d_in[1];
    const float* eb1 = (const float*)d_in[2];
    const float* ew2 = (const float*)d_in[3];
    const float* eb2 = (const float*)d_in[4];
    const float* ew3 = (const float*)d_in[5];
    const float* eb3 = (const float*)d_in[6];
    const float* cb  = (const float*)d_in[7];
    const float* dw1 = (const float*)d_in[8];
    const float* db1 = (const float*)d_in[9];
    const float* dw2 = (const float*)d_in[10];
    const float* db2 = (const float*)d_in[11];
    const float* dw3 = (const float*)d_in[12];
    const float* db3 = (const float*)d_in[13];
    float* out = (float*)d_out;

    // workspace: acc 16384 B | wbuf 131072 B | e C*131072 | rgn C*2130048
    // need(C) = 147456 + C*2261120   (C=64 -> ~144.9 MB)
    int C = 64;
    while (C > 1 && (size_t)147456 + (size_t)C * 2261120UL > ws_size) C >>= 1;

    char* base = (char*)d_ws;
    float*    acc = (float*)base;                            // 4096 floats
    ushort_t* wt  = (ushort_t*)(base + 16384);
    float*    cn  = (float*)(base + 16384 + 121856);
    ushort_t* e   = (ushort_t*)(base + 147456);
    char*     rgn = base + 147456 + (size_t)C * 131072UL;
    ushort_t* a1  = (ushort_t*)rgn;
    ushort_t* a2  = (ushort_t*)(rgn + (size_t)C * 1048576UL);
    ushort_t* d1p = (ushort_t*)rgn;                          // reuse (a1/a2 dead)

    zero_k<<<16, 256, 0, stream>>>(acc);
    prep_k<<<240, 256, 0, stream>>>(ew1, ew2, dw1, dw2, dw3, cb, wt, cn);

    for (int b0 = 0; b0 < 64; b0 += C) {
        const float* xc = x + (size_t)b0 * 196608UL;
        conv1_k   <<<dim3(1, C * 128), 256, 0, stream>>>(xc,  wt, eb1, a1);
        conv2_k   <<<dim3(1, C * 64),  256, 0, stream>>>(a1,  wt, eb2, a2);
        conv3_vq_k<<<dim3(C * 8),      256, 0, stream>>>(a2,  ew3, eb3, cb, cn, e, acc);
        pad_k     <<<dim3(C),          256, 0, stream>>>(d1p);
        dec1_k    <<<dim3(1, C * 64),  256, 0, stream>>>(e,   wt, db1, d1p);
        dec23_k   <<<dim3(2, C * 64),  256, 0, stream>>>(d1p, wt, db2, db3, xc, acc);
    }
    finalize_k<<<1, 64, 0, stream>>>(acc, out);
}

// Round 10
// 638.744 us; speedup vs baseline: 1.2242x; 1.0014x over previous
//
#include <hip/hip_runtime.h>
#include <hip/hip_bf16.h>

// VQ-VAE forward — NHWC bf16 intermediates, MFMA (16x16x32 bf16) for all convs.
// Outputs: [1.25*vq_mse, recon_mse, recon_mse]
//
// MFMA lane layouts (gfx950, HW-verified per guide):
//   A: m = lane&15, k = (lane>>4)*8 + j     (8 bf16 / lane)
//   B: n = lane&15, k = (lane>>4)*8 + j
//   D: n = lane&15, m = (lane>>4)*4 + reg   (4 f32 / lane)
//
// CHANNEL-INTERLEAVED storage: a producer with U=Cc/16 tiles stores tile u,
// column n16 (logical co = u*16+n16) at memory channel m = n16*U+u; consumers
// permute ci in weight prep: logical l(m) = (m%U)*16 + m/U.
//
// dec2+dec3 FUSED (dec23_k). R13: 1 atomic/block (580->409). R14: class-
// sequential stage 1 (409->323). R15: XCD swizzle (FETCH -55%, flat).
// R16: DPP kw-dedup + border init (319). R17/R18: occupancy probes (null —
// occupancy 43% didn't help; latency-via-occupancy dead). R19: cell-outer
// (455, regression) but quantified the binding resource: time tracks LOAD-
// INSTRUCTION count (~320cy marginal cost each, independent of cache level).
// R20: hoist (0,0) A-frags into A00[2][5] (A-loads 90->60): 307us (best) BUT
// the allocator kept VGPR=84 (its 6-waves/EU heuristic, 512/6~85, ignoring
// that LDS caps HW at 3 waves/EU) and spilled A00 (WRITE 0.26->131MB).
// R21: pin the occupancy target with amdgpu_waves_per_eu(3,3) so the
// allocator uses the ~168-reg budget and keeps A00 in registers. No
// algorithmic change vs R20.
//
// d1p [B][129][129][64]: interior (0,0)..(127,127); pad row/col 128 = 0.

typedef __attribute__((ext_vector_type(8))) short bf16x8;
typedef __attribute__((ext_vector_type(4))) float f32x4;
typedef __attribute__((ext_vector_type(4))) int i32x4;
typedef unsigned short ushort_t;

__device__ __forceinline__ ushort_t f2bf(float v) {
    __hip_bfloat16 h = __float2bfloat16(v);
    return *(ushort_t*)&h;
}
__device__ __forceinline__ float bf2f(ushort_t u) {
    __hip_bfloat16 h = *(__hip_bfloat16*)&u;
    return __bfloat162float(h);
}
__device__ __forceinline__ unsigned pack2r(float a, float b) {   // relu+pack
    return (unsigned)f2bf(fmaxf(a, 0.f)) | ((unsigned)f2bf(fmaxf(b, 0.f)) << 16);
}
// XCD-chunked bijective remap (requires nwg%8==0).
__device__ __forceinline__ int xcd_chunk(int flat, int nwg) {
    return (flat & 7) * (nwg >> 3) + (flat >> 3);
}
// DPP row-rotate of a 16B fragment within each 16-lane row.
// row_ror:N -> dst[n] = src[(n-N) mod 16].  0x121 = ror:1, 0x12F = ror:15.
#define ROR_FRAG(dst, src, CTRL)                                        \
    {                                                                   \
        i32x4 _a = __builtin_bit_cast(i32x4, src), _r;                  \
        _r[0] = __builtin_amdgcn_mov_dpp(_a[0], CTRL, 0xF, 0xF, false); \
        _r[1] = __builtin_amdgcn_mov_dpp(_a[1], CTRL, 0xF, 0xF, false); \
        _r[2] = __builtin_amdgcn_mov_dpp(_a[2], CTRL, 0xF, 0xF, false); \
        _r[3] = __builtin_amdgcn_mov_dpp(_a[3], CTRL, 0xF, 0xF, false); \
        dst = __builtin_bit_cast(bf16x8, _r);                           \
    }

// Accumulator layout (fp32, 4096 floats = 16 KB at workspace base):
//   vq  partials: acc[slot*32],        slot = 0..63   (128 B apart)
//   mse partials: acc[2048 + slot*32], slot = 0..63
//
// Transformed-weight layout in wbuf (elements of bf16, at base+16384):
//   W1T  @ 0      [co32][k32]            (k=ci*9+kh*3+kw, pad 27->32)
//   W2T  @ 1024   [t9][co64][ci32]       (ci permuted: l2(ci))
//   WD1  @ 19456  [t9][co64][k32]        (k<16 = ci natural, else 0)
//   WD2  @ 37888  [t9][kc2][co32][ci32]  (ci permuted: l4(kc*32+ci))
//   WD3  @ 56320  [t9][co16][ci32]       (taps FLIPPED: src 8-t; ci perm l2; co>=3 -> 0)
//   cn (fp32, 512) @ byte offset 121856 within wbuf

__global__ void zero_k(float* __restrict__ acc) {
    acc[blockIdx.x * 256 + threadIdx.x] = 0.f;
}

__global__ __launch_bounds__(256) void prep_k(
        const float* __restrict__ ew1, const float* __restrict__ ew2,
        const float* __restrict__ dw1, const float* __restrict__ dw2,
        const float* __restrict__ dw3, const float* __restrict__ cb,
        ushort_t* __restrict__ wt, float* __restrict__ cn) {
    int idx = blockIdx.x * 256 + threadIdx.x;
    if (idx < 1024) {
        int co = idx >> 5, k = idx & 31;
        wt[idx] = (k < 27) ? f2bf(ew1[co * 27 + k]) : (ushort_t)0;
    } else if (idx < 19456) {
        int i = idx - 1024;
        int t = i >> 11, co = (i >> 5) & 63, ci = i & 31;
        int lci = ((ci & 1) << 4) | (ci >> 1);                 // l2 (conv1 U=2)
        wt[idx] = f2bf(ew2[co * 288 + lci * 9 + t]);
    } else if (idx < 37888) {
        int i = idx - 19456;
        int t = i >> 11, co = (i >> 5) & 63, k = i & 31;
        wt[idx] = (k < 16) ? f2bf(dw1[k * 576 + co * 9 + t]) : (ushort_t)0;
    } else if (idx < 56320) {
        int i = idx - 37888;
        int t = i >> 11, kc = (i >> 10) & 1, co = (i >> 5) & 31, ci = i & 31;
        int m = kc * 32 + ci;
        int lci = ((m & 3) << 4) | (m >> 2);                   // l4 (dec1 U=4)
        wt[idx] = f2bf(dw2[lci * 288 + co * 9 + t]);
    } else if (idx < 60928) {
        int i = idx - 56320;
        int t = i >> 9, co = (i >> 5) & 15, ci = i & 31;
        int lci = ((ci & 1) << 4) | (ci >> 1);                 // l2 (dec2 U=2)
        wt[idx] = (co < 3) ? f2bf(dw3[lci * 27 + co * 9 + (8 - t)]) : (ushort_t)0;
    } else if (idx < 61440) {
        int k = idx - 60928;
        float s = 0.f;
        #pragma unroll
        for (int d = 0; d < 16; ++d) { float v = cb[k * 16 + d]; s += v * v; }
        cn[k] = s;
    }
}

// ---------------- zero the pad borders of d1p (one block per image) ---------
__global__ __launch_bounds__(256) void pad_k(ushort_t* __restrict__ d1p) {
    const int img = blockIdx.x, tid = threadIdx.x;
    const uint4 z = (uint4){0, 0, 0, 0};
    uint4* b1 = (uint4*)(d1p + (size_t)img * 1065024);   // 129*129*64 elems
    for (int i = tid; i < 1032; i += 256) b1[132096 + i] = z;   // row 128
    for (int i = tid; i < 1024; i += 256) {                     // col 128
        int r = i >> 3, u = i & 7;
        b1[(r * 129 + 128) * 8 + u] = z;
    }
}

// ---------------- conv1 MFMA: x NCHW fp32 -> a1 [B,128,128,32] (interleaved)
__global__ __launch_bounds__(256, 4) void conv1_k(const float* __restrict__ x,
        const ushort_t* __restrict__ wt, const float* __restrict__ bias,
        ushort_t* __restrict__ a1) {
    const int L = xcd_chunk(blockIdx.y, gridDim.y);
    const int b = L >> 7, oh = L & 127;
    const int tid = threadIdx.x;
    __shared__ __align__(16) ushort_t sX[9 * 264];   // [ci*3+kh][iw+1 (258 used)]
    __shared__ int sOff[32];
    for (int i = tid; i < 9 * 264 / 2; i += 256) ((unsigned*)sX)[i] = 0u;
    if (tid < 32) {
        int k = tid, off = 0;
        if (k < 27) { int ci = k / 9, r9 = k % 9, kh = r9 / 3, kw = r9 % 3;
                      off = (ci * 3 + kh) * 264 + kw; }
        sOff[tid] = off;
    }
    __syncthreads();
    #pragma unroll
    for (int it = 0; it < 9; ++it) {
        int slot = it * 256 + tid;                  // 2304 = 3ci * 3kh * 256iw
        int ci = slot / 768, r = slot % 768, kh = r >> 8, iw = r & 255;
        int ih = 2 * oh + kh - 1;
        float v = ((unsigned)ih < 256u) ? x[(long)(b * 3 + ci) * 65536 + ih * 256 + iw] : 0.f;
        sX[(ci * 3 + kh) * 264 + iw + 1] = f2bf(v);
    }
    __syncthreads();
    const int lane = tid & 63, wave = tid >> 6, q = lane >> 4, n16 = lane & 15;
    bf16x8 Bw[2];
    #pragma unroll
    for (int u = 0; u < 2; ++u)
        Bw[u] = *(const bf16x8*)(wt + (u * 16 + n16) * 32 + q * 8);
    f32x4 acc[2][2];
    #pragma unroll
    for (int u = 0; u < 2; ++u) {
        float bz = bias[u * 16 + n16];
        acc[0][u] = (f32x4){bz, bz, bz, bz};
        acc[1][u] = (f32x4){bz, bz, bz, bz};
    }
    #pragma unroll
    for (int mf = 0; mf < 2; ++mf) {
        const int m2 = 2 * (wave * 32 + mf * 16 + n16);
        ushort_t av[8];
        #pragma unroll
        for (int j = 0; j < 8; ++j) {
            int k = q * 8 + j;
            av[j] = (k < 27) ? sX[sOff[k] + m2] : (ushort_t)0;
        }
        bf16x8 A = *(bf16x8*)av;
        #pragma unroll
        for (int u = 0; u < 2; ++u)
            acc[mf][u] = __builtin_amdgcn_mfma_f32_16x16x32_bf16(A, Bw[u], acc[mf][u], 0, 0, 0);
    }
    #pragma unroll
    for (int mf = 0; mf < 2; ++mf)
        #pragma unroll
        for (int r = 0; r < 4; ++r) {
            int ow = wave * 32 + mf * 16 + q * 4 + r;
            *(unsigned*)(a1 + ((long)(b * 128 + oh) * 128 + ow) * 32 + n16 * 2) =
                pack2r(acc[mf][0][r], acc[mf][1][r]);
        }
}

// ---------------- conv2 MFMA: a1 -> a2 [B,64,64,64] (interleaved) -----------
__global__ __launch_bounds__(256, 4) void conv2_k(const ushort_t* __restrict__ a1,
        const ushort_t* __restrict__ wt, const float* __restrict__ bias,
        ushort_t* __restrict__ a2) {
    const int L = xcd_chunk(blockIdx.y, gridDim.y);
    const int b = L >> 6, oh = L & 63;
    const int tid = threadIdx.x;
    // parity-split: [kh3][p2][c66][ci32 pad40]
    __shared__ __align__(16) ushort_t sA[3 * 2 * 66 * 40];
    uint4* z4 = (uint4*)sA;
    #pragma unroll
    for (int it = 0; it < 8; ++it) {
        int slot = it * 256 + tid;
        if (slot < 1980) z4[slot] = (uint4){0, 0, 0, 0};
    }
    __syncthreads();
    #pragma unroll
    for (int it = 0; it < 6; ++it) {
        int slot = it * 256 + tid;                    // 1536 = 3kh*128iw*4
        if (slot < 1536) {
            int kh = slot >> 9, rem = slot & 511, iw = rem >> 2, ci8 = (rem & 3) << 3;
            int ih = 2 * oh + kh - 1;
            if ((unsigned)ih < 128u) {
                uint4 v = *(const uint4*)(a1 + ((long)(b * 128 + ih) * 128 + iw) * 32 + ci8);
                int idx = iw + 2, p = idx & 1, c = idx >> 1;
                *(uint4*)&sA[((kh * 2 + p) * 66 + c) * 40 + ci8] = v;
            }
        }
    }
    __syncthreads();
    const int lane = tid & 63, wave = tid >> 6, q = lane >> 4, n16 = lane & 15;
    f32x4 acc[4];
    #pragma unroll
    for (int u = 0; u < 4; ++u) {
        float bz = bias[u * 16 + n16];
        acc[u] = (f32x4){bz, bz, bz, bz};
    }
    const int ow = wave * 16 + n16;   // A row (m)
    #pragma unroll
    for (int t = 0; t < 9; ++t) {
        const int kh = t / 3, kw = t % 3;
        const int p = (kw == 1) ? 0 : 1;
        const int c = (kw == 0) ? ow : ow + 1;
        bf16x8 A = *(bf16x8*)&sA[((kh * 2 + p) * 66 + c) * 40 + q * 8];
        #pragma unroll
        for (int u = 0; u < 4; ++u) {
            bf16x8 B = *(const bf16x8*)(wt + 1024 + t * 2048 + (u * 16 + n16) * 32 + q * 8);
            acc[u] = __builtin_amdgcn_mfma_f32_16x16x32_bf16(A, B, acc[u], 0, 0, 0);
        }
    }
    #pragma unroll
    for (int r = 0; r < 4; ++r) {
        int owo = wave * 16 + q * 4 + r;
        uint2 pk;
        pk.x = pack2r(acc[0][r], acc[1][r]);
        pk.y = pack2r(acc[2][r], acc[3][r]);
        *(uint2*)(a2 + ((long)(b * 64 + oh) * 64 + owo) * 64 + n16 * 4) = pk;
    }
}

// ---------------- conv3 (1x1) + VQ + loss, 2 px/thread ----------------------
__global__ __launch_bounds__(256) void conv3_vq_k(const ushort_t* __restrict__ a2,
        const float* __restrict__ w3, const float* __restrict__ b3,
        const float* __restrict__ cb, const float* __restrict__ cn,
        ushort_t* __restrict__ e, float* __restrict__ acc) {
    const int base = blockIdx.x * 512 + threadIdx.x;   // px0 = base, px1 = base+256
    __shared__ float sred[4];
    float z[2][16];
    #pragma unroll
    for (int p = 0; p < 2; ++p)
        #pragma unroll
        for (int d = 0; d < 16; ++d) z[p][d] = b3[d];
    #pragma unroll
    for (int p = 0; p < 2; ++p) {
        const ushort_t* arow = a2 + (long)(base + p * 256) * 64;
        #pragma unroll
        for (int c8 = 0; c8 < 8; ++c8) {
            uint4 raw = *(const uint4*)(arow + c8 * 8);
            ushort_t us[8];
            *(uint4*)us = raw;
            #pragma unroll
            for (int j = 0; j < 8; ++j) {
                int m = c8 * 8 + j;
                int lci = ((m & 3) << 4) | (m >> 2);          // l4
                float a = bf2f(us[j]);
                #pragma unroll
                for (int d = 0; d < 16; ++d)
                    z[p][d] = fmaf(a, w3[d * 64 + lci], z[p][d]);
            }
        }
    }
    const float4* cb4 = (const float4*)cb;
    float best0 = 1e30f, best1 = 1e30f; int bi0 = 0, bi1 = 0;
    for (int k = 0; k < 512; ++k) {
        float4 c0 = cb4[k * 4 + 0], c1 = cb4[k * 4 + 1];
        float4 c2 = cb4[k * 4 + 2], c3 = cb4[k * 4 + 3];
        float nk = cn[k];
        float d0 = z[0][0]*c0.x + z[0][1]*c0.y + z[0][2]*c0.z + z[0][3]*c0.w
                 + z[0][4]*c1.x + z[0][5]*c1.y + z[0][6]*c1.z + z[0][7]*c1.w
                 + z[0][8]*c2.x + z[0][9]*c2.y + z[0][10]*c2.z + z[0][11]*c2.w
                 + z[0][12]*c3.x + z[0][13]*c3.y + z[0][14]*c3.z + z[0][15]*c3.w;
        float d1 = z[1][0]*c0.x + z[1][1]*c0.y + z[1][2]*c0.z + z[1][3]*c0.w
                 + z[1][4]*c1.x + z[1][5]*c1.y + z[1][6]*c1.z + z[1][7]*c1.w
                 + z[1][8]*c2.x + z[1][9]*c2.y + z[1][10]*c2.z + z[1][11]*c2.w
                 + z[1][12]*c3.x + z[1][13]*c3.y + z[1][14]*c3.z + z[1][15]*c3.w;
        float dist0 = nk - 2.f * d0, dist1 = nk - 2.f * d1;
        if (dist0 < best0) { best0 = dist0; bi0 = k; }
        if (dist1 < best1) { best1 = dist1; bi1 = k; }
    }
    float lsum = 0.f;
    #pragma unroll
    for (int d = 0; d < 16; ++d) {
        float q0 = cb[bi0 * 16 + d], q1 = cb[bi1 * 16 + d];
        float f0 = q0 - z[0][d], f1 = q1 - z[1][d];
        lsum += f0 * f0 + f1 * f1;
        e[(long)base * 16 + d] = f2bf(q0);
        e[(long)(base + 256) * 16 + d] = f2bf(q1);
    }
    #pragma unroll
    for (int off = 32; off > 0; off >>= 1) lsum += __shfl_down(lsum, off, 64);
    if ((threadIdx.x & 63) == 0) sred[threadIdx.x >> 6] = lsum;
    __syncthreads();
    if (threadIdx.x == 0)
        atomicAdd(&acc[(blockIdx.x & 63) << 5],
                  sred[0] + sred[1] + sred[2] + sred[3]);
}

// ---------------- dec1 MFMA: e -> d1p [B,129,129,64] (interleaved) ----------
__global__ __launch_bounds__(256, 4) void dec1_k(const ushort_t* __restrict__ e,
        const ushort_t* __restrict__ wt, const float* __restrict__ bias,
        ushort_t* __restrict__ d1p) {
    const int L = xcd_chunk(blockIdx.y, gridDim.y);
    const int b = L >> 6, i = L & 63;
    const int tid = threadIdx.x;
    __shared__ __align__(16) ushort_t sE[2 * 66 * 24];  // [dh2][j66][ci16 pad24]
    uint4* z4 = (uint4*)sE;
    #pragma unroll
    for (int it = 0; it < 2; ++it) {
        int slot = it * 256 + tid;
        if (slot < 396) z4[slot] = (uint4){0, 0, 0, 0};
    }
    __syncthreads();
    {
        int dh = tid >> 7, rem = tid & 127, j = rem >> 1, ci8 = (rem & 1) * 8;
        if (i + dh < 64) {
            uint4 v = *(const uint4*)(e + ((long)((b * 64 + i + dh) * 64 + j)) * 16 + ci8);
            *(uint4*)&sE[(dh * 66 + j) * 24 + ci8] = v;
        }
    }
    __syncthreads();
    const int lane = tid & 63, wave = tid >> 6, q = lane >> 4, n16 = lane & 15;
    f32x4 acc[4][4];   // [class ph*2+pw][ntile]
    #pragma unroll
    for (int u = 0; u < 4; ++u) {
        float bz = bias[u * 16 + n16];
        #pragma unroll
        for (int c = 0; c < 4; ++c) acc[c][u] = (f32x4){bz, bz, bz, bz};
    }
    const int jl = wave * 16 + n16;
    #pragma unroll
    for (int t = 0; t < 9; ++t) {
        const int kh = t / 3, kw = t % 3;
        const int dh = (kh == 0) ? 1 : 0, dw = (kw == 0) ? 1 : 0;
        const int cls = ((kh != 1) ? 2 : 0) | ((kw != 1) ? 1 : 0);
        bf16x8 A = *(bf16x8*)&sE[(dh * 66 + jl + dw) * 24 + (q & 1) * 8];
        #pragma unroll
        for (int u = 0; u < 4; ++u) {
            bf16x8 B = *(const bf16x8*)(wt + 19456 + t * 2048 + (u * 16 + n16) * 32 + q * 8);
            acc[cls][u] = __builtin_amdgcn_mfma_f32_16x16x32_bf16(A, B, acc[cls][u], 0, 0, 0);
        }
    }
    #pragma unroll
    for (int ph = 0; ph < 2; ++ph)
        #pragma unroll
        for (int pw = 0; pw < 2; ++pw)
            #pragma unroll
            for (int r = 0; r < 4; ++r) {
                int oh = 2 * i + ph;
                int ow = 2 * (wave * 16 + q * 4 + r) + pw;
                uint2 pk;
                pk.x = pack2r(acc[ph * 2 + pw][0][r], acc[ph * 2 + pw][1][r]);
                pk.y = pack2r(acc[ph * 2 + pw][2][r], acc[ph * 2 + pw][3][r]);
                *(uint2*)(d1p + (size_t)b * 1065024 + ((long)oh * 129 + ow) * 64 + n16 * 4) = pk;
            }
}

// ---------------- dec23: fused convT(64->32,s2) + conv(32->3) + MSE ---------
// Block: output rows 4*i4..4*i4+3, cols j0..j0+127 (j0 = bx*128).
// Stage 1 (R14+R20): wave = one a-row, 5 cells, class-sequential acc reuse.
// (dh,dw)=(0,0) A-fragments hoisted into A00[2][5] once per wave (taps
// 4,5,7,8). R21: amdgpu_waves_per_eu(3,3) pins the allocator's occupancy
// target to what LDS already enforces (3 blocks/CU = 3 waves/EU), giving
// it the ~168-VGPR budget so A00 stays in registers (R20 spilled at 84).
// Stage 2 (R16): kw=1 frags from sT + DPP row_ror for kw=0/2; border init.
__global__ __launch_bounds__(256)
__attribute__((amdgpu_waves_per_eu(3, 3)))
void dec23_k(const ushort_t* __restrict__ d1p,
        const ushort_t* __restrict__ wt, const float* __restrict__ db2,
        const float* __restrict__ db3, const float* __restrict__ x,
        float* __restrict__ acc) {
    const int flat = blockIdx.y * 2 + blockIdx.x;
    const int L = xcd_chunk(flat, gridDim.y * 2);
    const int bx = L & 1, byl = L >> 1;
    const int b = byl >> 6, i4 = byl & 63;
    const int j0 = bx << 7;
    const int tid = threadIdx.x;
    const int lane = tid & 63, wave = tid >> 6, q = lane >> 4, n16 = lane & 15;

    __shared__ __align__(16) ushort_t sT[6 * 132 * 32];   // [R'6][c'132][ch32] 50688 B
    __shared__ float sred[4];

    // ---- targeted border init (interior is fully written by stage 1) ----
    // unwritten-but-read: col 0 (bx=0), col 129 (bx=1), row 0 (i4=0), row 5 (i4=63)
    {
        unsigned* sw = (unsigned*)sT;
        if (tid < 96) {
            int r6 = tid >> 4, w16 = tid & 15;
            int c = (bx == 0) ? 0 : 129;
            sw[r6 * 2112 + c * 16 + w16] = 0u;
        }
        if (i4 == 0)
            for (int i = tid; i < 2080; i += 256) sw[i] = 0u;
        if (i4 == 63)
            for (int i = tid; i < 2080; i += 256) sw[5 * 2112 + i] = 0u;
    }
    __syncthreads();

    // ---- stage 1: dec2 into sT (class-sequential, one a-row per wave) ----
    const int bb0 = (j0 >> 1) - 1;
    const ushort_t* dbase = d1p + (size_t)b * 1065024;
    const int aidx = wave;
    const int a = 2 * i4 + aidx - 1;
    const bool doP0 = (aidx != 0);    // d2 row 2a+0 in tile?
    const bool doP1 = (aidx != 3);    // d2 row 2a+1 in tile?
    // row pointers, OOB rows -> zero pad row 128
    int r0 = a, r1 = a + 1;
    r0 = ((unsigned)r0 <= 128u) ? r0 : 128;
    r1 = ((unsigned)r1 <= 128u) ? r1 : 128;
    const ushort_t* rowp0 = dbase + (long)r0 * 8256;   // 129*64
    const ushort_t* rowp1 = dbase + (long)r1 * 8256;
    // per-lane col element-offsets, OOB cols -> zero pad col 128
    int colo[5][2];
    #pragma unroll
    for (int cell = 0; cell < 5; ++cell)
        #pragma unroll
        for (int dw = 0; dw < 2; ++dw) {
            int col = bb0 + cell * 16 + n16 + dw;
            colo[cell][dw] = (((unsigned)col <= 128u) ? col : 128) * 64;
        }
    const float bz0 = db2[n16], bz1 = db2[16 + n16];
    f32x4 a5[2][5];                                    // [u][cell], per class

    // R20: hoisted (dh,dw)=(0,0) fragments — used by taps 4,5,7,8
    bf16x8 A00[2][5];                                  // [kc][cell]
    #pragma unroll
    for (int kc = 0; kc < 2; ++kc)
        #pragma unroll
        for (int cell = 0; cell < 5; ++cell)
            A00[kc][cell] = *(const bf16x8*)(rowp0 + colo[cell][0] + kc * 32 + q * 8);

#define INIT5()                                                                     \
    _Pragma("unroll")                                                               \
    for (int cell = 0; cell < 5; ++cell) {                                          \
        a5[0][cell] = (f32x4){bz0, bz0, bz0, bz0};                                  \
        a5[1][cell] = (f32x4){bz1, bz1, bz1, bz1};                                  \
    }
#define TAP5(T, DH, DW)                                                             \
    {                                                                               \
        const ushort_t* wb = wt + 37888 + (T) * 2048;                               \
        const ushort_t* rp = (DH) ? rowp1 : rowp0;                                  \
        _Pragma("unroll")                                                           \
        for (int kc = 0; kc < 2; ++kc) {                                            \
            bf16x8 B0 = *(const bf16x8*)(wb + kc * 1024 + n16 * 32 + q * 8);        \
            bf16x8 B1 = *(const bf16x8*)(wb + kc * 1024 + (16 + n16) * 32 + q * 8); \
            _Pragma("unroll")                                                       \
            for (int cell = 0; cell < 5; ++cell) {                                  \
                bf16x8 Av = *(const bf16x8*)(rp + colo[cell][DW] + kc * 32 + q * 8);\
                a5[0][cell] = __builtin_amdgcn_mfma_f32_16x16x32_bf16(              \
                    Av, B0, a5[0][cell], 0, 0, 0);                                  \
                a5[1][cell] = __builtin_amdgcn_mfma_f32_16x16x32_bf16(              \
                    Av, B1, a5[1][cell], 0, 0, 0);                                  \
            }                                                                       \
        }                                                                           \
    }
#define TAP5H(T)                                                                    \
    {                                                                               \
        const ushort_t* wb = wt + 37888 + (T) * 2048;                               \
        _Pragma("unroll")                                                           \
        for (int kc = 0; kc < 2; ++kc) {                                            \
            bf16x8 B0 = *(const bf16x8*)(wb + kc * 1024 + n16 * 32 + q * 8);        \
            bf16x8 B1 = *(const bf16x8*)(wb + kc * 1024 + (16 + n16) * 32 + q * 8); \
            _Pragma("unroll")                                                       \
            for (int cell = 0; cell < 5; ++cell) {                                  \
                a5[0][cell] = __builtin_amdgcn_mfma_f32_16x16x32_bf16(              \
                    A00[kc][cell], B0, a5[0][cell], 0, 0, 0);                       \
                a5[1][cell] = __builtin_amdgcn_mfma_f32_16x16x32_bf16(              \
                    A00[kc][cell], B1, a5[1][cell], 0, 0, 0);                       \
            }                                                                       \
        }                                                                           \
    }
#define EPI5(PH, PW)                                                                \
    {                                                                               \
        int R = 2 * a + (PH);                                                       \
        if ((unsigned)R < 256u) {                                                   \
            int Rp = R - 4 * i4 + 1;                                                \
            _Pragma("unroll")                                                       \
            for (int cell = 0; cell < 5; ++cell)                                    \
                _Pragma("unroll")                                                   \
                for (int r = 0; r < 4; ++r) {                                       \
                    int lq = cell * 16 + q * 4 + r;                                 \
                    int cp = 2 * lq + (PW) - 1;                                     \
                    int cg = 2 * (bb0 + lq) + (PW);                                 \
                    if ((unsigned)cg < 256u && (unsigned)cp < 130u)                 \
                        *(unsigned*)&sT[Rp * 4224 + cp * 32 + n16 * 2] =            \
                            pack2r(a5[0][cell][r], a5[1][cell][r]);                 \
                }                                                                   \
        }                                                                           \
    }
    // taps by class: cls = (kh!=1)*2 | (kw!=1); dh=(kh==0), dw=(kw==0)
    // (0,0)-taps (4,5,7,8) use hoisted A00 — one per class.
    if (doP0) {
        INIT5(); TAP5H(4); EPI5(0, 0);                             // cls0: (1,1)
        INIT5(); TAP5(3, 0, 1); TAP5H(5); EPI5(0, 1);              // cls1: (1,0),(1,2)
    }
    if (doP1) {
        INIT5(); TAP5(1, 1, 0); TAP5H(7); EPI5(1, 0);              // cls2: (0,1),(2,1)
        INIT5(); TAP5(0, 1, 1); TAP5(2, 1, 0); TAP5(6, 0, 1); TAP5H(8);
        EPI5(1, 1);                                                // cls3: corners
    }
#undef INIT5
#undef TAP5
#undef TAP5H
#undef EPI5
    __syncthreads();

    // ---- stage 2: dec3 conv + MSE (wave -> row oh, cols j0..j0+127) ----
    float bz3 = (n16 < 3) ? db3[n16] : 0.f;
    f32x4 a4[8];
    #pragma unroll
    for (int mf = 0; mf < 8; ++mf) a4[mf] = (f32x4){bz3, bz3, bz3, bz3};
    const int oh = 4 * i4 + wave;
    const bool is_l0 = (n16 == 0), is_l15 = (n16 == 15);
    #pragma unroll
    for (int kh = 0; kh < 3; ++kh) {
        const ushort_t* srow = &sT[(wave + kh) * 4224];
        bf16x8 Bk0 = *(const bf16x8*)(wt + 56320 + (kh * 3 + 0) * 512 + n16 * 32 + q * 8);
        bf16x8 Bk1 = *(const bf16x8*)(wt + 56320 + (kh * 3 + 1) * 512 + n16 * 32 + q * 8);
        bf16x8 Bk2 = *(const bf16x8*)(wt + 56320 + (kh * 3 + 2) * 512 + n16 * 32 + q * 8);
        // kw=1 fragments (c = m+1) + edge fragments
        bf16x8 G[8];
        #pragma unroll
        for (int mf = 0; mf < 8; ++mf)
            G[mf] = *(const bf16x8*)(srow + (mf * 16 + n16 + 1) * 32 + q * 8);
        bf16x8 E  = *(const bf16x8*)(srow + n16 * 32 + q * 8);          // lane0 -> c=0
        bf16x8 E2 = *(const bf16x8*)(srow + (114 + n16) * 32 + q * 8);  // lane15 -> c=129
        #pragma unroll
        for (int mf = 0; mf < 8; ++mf)
            a4[mf] = __builtin_amdgcn_mfma_f32_16x16x32_bf16(G[mf], Bk1, a4[mf], 0, 0, 0);
        // kw=0 (c = m): lane n takes lane n-1's G; lane0 patched from prev frag
        bf16x8 P = E;
        #pragma unroll
        for (int mf = 0; mf < 8; ++mf) {
            bf16x8 Qm; ROR_FRAG(Qm, G[mf], 0x121);      // ror:1 -> src[n-1]
            bf16x8 kw0 = is_l0 ? P : Qm;
            a4[mf] = __builtin_amdgcn_mfma_f32_16x16x32_bf16(kw0, Bk0, a4[mf], 0, 0, 0);
            P = Qm;
        }
        // kw=2 (c = m+2): lane n takes lane n+1's G; lane15 patched from next frag
        P = E2;
        #pragma unroll
        for (int mf = 7; mf >= 0; --mf) {
            bf16x8 Rm; ROR_FRAG(Rm, G[mf], 0x12F);      // ror:15 -> src[n+1]
            bf16x8 kw2 = is_l15 ? P : Rm;
            a4[mf] = __builtin_amdgcn_mfma_f32_16x16x32_bf16(kw2, Bk2, a4[mf], 0, 0, 0);
            P = Rm;
        }
    }
    float lsum = 0.f;
    if (n16 < 3) {
        const float* xrow = x + ((long)(b * 3 + n16) * 256 + oh) * 256 + j0;
        #pragma unroll
        for (int mf = 0; mf < 8; ++mf)
            #pragma unroll
            for (int r = 0; r < 4; ++r) {
                int ow = mf * 16 + q * 4 + r;
                float df = a4[mf][r] - xrow[ow];
                lsum += df * df;
            }
    }
    #pragma unroll
    for (int off = 32; off > 0; off >>= 1) lsum += __shfl_down(lsum, off, 64);
    if (lane == 0) sred[wave] = lsum;
    __syncthreads();
    if (tid == 0)
        atomicAdd(&acc[2048 + ((byl & 63) << 5)],
                  sred[0] + sred[1] + sred[2] + sred[3]);
}

__global__ void finalize_k(const float* __restrict__ acc, float* __restrict__ out) {
    int t = threadIdx.x;                 // 64 threads
    float v = acc[t << 5];
    float m = acc[2048 + (t << 5)];
    #pragma unroll
    for (int off = 32; off > 0; off >>= 1) {
        v += __shfl_down(v, off, 64);
        m += __shfl_down(m, off, 64);
    }
    if (t == 0) {
        float eq  = 1.25f * v / 4194304.f;     // 262144 px * 16 d
        float mse = m / 12582912.f;            // 64 * 3 * 256 * 256
        out[0] = eq;
        out[1] = mse;
        out[2] = mse;
    }
}

extern "C" void kernel_launch(void* const* d_in, const int* in_sizes, int n_in,
                              void* d_out, int out_size, void* d_ws, size_t ws_size,
                              hipStream_t stream) {
    (void)in_sizes; (void)n_in; (void)out_size;
    const float* x   = (const float*)d_in[0];
    const float* ew1 = (const float*)d_in[1];
    const float* eb1 = (const float*)d_in[2];
    const float* ew2 = (const float*)d_in[3];
    const float* eb2 = (const float*)d_in[4];
    const float* ew3 = (const float*)d_in[5];
    const float* eb3 = (const float*)d_in[6];
    const float* cb  = (const float*)d_in[7];
    const float* dw1 = (const float*)d_in[8];
    const float* db1 = (const float*)d_in[9];
    const float* dw2 = (const float*)d_in[10];
    const float* db2 = (const float*)d_in[11];
    const float* dw3 = (const float*)d_in[12];
    const float* db3 = (const float*)d_in[13];
    float* out = (float*)d_out;

    // workspace: acc 16384 B | wbuf 131072 B | e C*131072 | rgn C*2130048
    // need(C) = 147456 + C*2261120   (C=64 -> ~144.9 MB)
    int C = 64;
    while (C > 1 && (size_t)147456 + (size_t)C * 2261120UL > ws_size) C >>= 1;

    char* base = (char*)d_ws;
    float*    acc = (float*)base;                            // 4096 floats
    ushort_t* wt  = (ushort_t*)(base + 16384);
    float*    cn  = (float*)(base + 16384 + 121856);
    ushort_t* e   = (ushort_t*)(base + 147456);
    char*     rgn = base + 147456 + (size_t)C * 131072UL;
    ushort_t* a1  = (ushort_t*)rgn;
    ushort_t* a2  = (ushort_t*)(rgn + (size_t)C * 1048576UL);
    ushort_t* d1p = (ushort_t*)rgn;                          // reuse (a1/a2 dead)

    zero_k<<<16, 256, 0, stream>>>(acc);
    prep_k<<<240, 256, 0, stream>>>(ew1, ew2, dw1, dw2, dw3, cb, wt, cn);

    for (int b0 = 0; b0 < 64; b0 += C) {
        const float* xc = x + (size_t)b0 * 196608UL;
        conv1_k   <<<dim3(1, C * 128), 256, 0, stream>>>(xc,  wt, eb1, a1);
        conv2_k   <<<dim3(1, C * 64),  256, 0, stream>>>(a1,  wt, eb2, a2);
        conv3_vq_k<<<dim3(C * 8),      256, 0, stream>>>(a2,  ew3, eb3, cb, cn, e, acc);
        pad_k     <<<dim3(C),          256, 0, stream>>>(d1p);
        dec1_k    <<<dim3(1, C * 64),  256, 0, stream>>>(e,   wt, db1, d1p);
        dec23_k   <<<dim3(2, C * 64),  256, 0, stream>>>(d1p, wt, db2, db3, xc, acc);
    }
    finalize_k<<<1, 64, 0, stream>>>(acc, out);
}

// Round 11
// 628.533 us; speedup vs baseline: 1.2441x; 1.0162x over previous
//
#include <hip/hip_runtime.h>
#include <hip/hip_bf16.h>

// VQ-VAE forward — NHWC bf16 intermediates, MFMA (16x16x32 bf16) for all convs.
// Outputs: [1.25*vq_mse, recon_mse, recon_mse]
//
// MFMA lane layouts (gfx950, HW-verified per guide):
//   A: m = lane&15, k = (lane>>4)*8 + j     (8 bf16 / lane)
//   B: n = lane&15, k = (lane>>4)*8 + j
//   D: n = lane&15, m = (lane>>4)*4 + reg   (4 f32 / lane)
//
// CHANNEL-INTERLEAVED storage: a producer with U=Cc/16 tiles stores tile u,
// column n16 (logical co = u*16+n16) at memory channel m = n16*U+u; consumers
// permute ci in weight prep: logical l(m) = (m%U)*16 + m/U.
//
// dec2+dec3 FUSED (dec23_k). R13: 1 atomic/block (580->409). R14: class-
// sequential stage 1 (409->323). R15: XCD swizzle (FETCH -55%, flat).
// R16: DPP kw-dedup + border init (319). R17/R18: occupancy probes (null).
// R19: quantified binding resource — time tracks VMEM load-instruction count
// (~47cy/instr CU line-throughput; each instr touches ~16 lines = optimal
// packing already). R20: hoist (0,0) A-frags (A-loads 90->60): 307 BUT
// allocator spilled A00 (WRITE 0.26->131MB) at VGPR=84. R21: waves_per_eu
// attr = no-op.
// R22: EMPIRICAL launch_bounds MAPPING. Session data: (256,3)->84,
// (256,4)->60, (256,5)->48 == 512/(2N): the 2nd arg is DOUBLED into
// amdgpu-waves-per-eu. All prior rounds ran at HALF the intended budget.
// Fix: __launch_bounds__(256,1) -> budget ~256; allocator settles at need
// (~130 <= 168) so HW occupancy stays LDS-capped at 3 blocks/CU and A00
// stays in registers. WRITE_SIZE is the spill canary.
//
// d1p [B][129][129][64]: interior (0,0)..(127,127); pad row/col 128 = 0.

typedef __attribute__((ext_vector_type(8))) short bf16x8;
typedef __attribute__((ext_vector_type(4))) float f32x4;
typedef __attribute__((ext_vector_type(4))) int i32x4;
typedef unsigned short ushort_t;

__device__ __forceinline__ ushort_t f2bf(float v) {
    __hip_bfloat16 h = __float2bfloat16(v);
    return *(ushort_t*)&h;
}
__device__ __forceinline__ float bf2f(ushort_t u) {
    __hip_bfloat16 h = *(__hip_bfloat16*)&u;
    return __bfloat162float(h);
}
__device__ __forceinline__ unsigned pack2r(float a, float b) {   // relu+pack
    return (unsigned)f2bf(fmaxf(a, 0.f)) | ((unsigned)f2bf(fmaxf(b, 0.f)) << 16);
}
// XCD-chunked bijective remap (requires nwg%8==0).
__device__ __forceinline__ int xcd_chunk(int flat, int nwg) {
    return (flat & 7) * (nwg >> 3) + (flat >> 3);
}
// DPP row-rotate of a 16B fragment within each 16-lane row.
// row_ror:N -> dst[n] = src[(n-N) mod 16].  0x121 = ror:1, 0x12F = ror:15.
#define ROR_FRAG(dst, src, CTRL)                                        \
    {                                                                   \
        i32x4 _a = __builtin_bit_cast(i32x4, src), _r;                  \
        _r[0] = __builtin_amdgcn_mov_dpp(_a[0], CTRL, 0xF, 0xF, false); \
        _r[1] = __builtin_amdgcn_mov_dpp(_a[1], CTRL, 0xF, 0xF, false); \
        _r[2] = __builtin_amdgcn_mov_dpp(_a[2], CTRL, 0xF, 0xF, false); \
        _r[3] = __builtin_amdgcn_mov_dpp(_a[3], CTRL, 0xF, 0xF, false); \
        dst = __builtin_bit_cast(bf16x8, _r);                           \
    }

// Accumulator layout (fp32, 4096 floats = 16 KB at workspace base):
//   vq  partials: acc[slot*32],        slot = 0..63   (128 B apart)
//   mse partials: acc[2048 + slot*32], slot = 0..63
//
// Transformed-weight layout in wbuf (elements of bf16, at base+16384):
//   W1T  @ 0      [co32][k32]            (k=ci*9+kh*3+kw, pad 27->32)
//   W2T  @ 1024   [t9][co64][ci32]       (ci permuted: l2(ci))
//   WD1  @ 19456  [t9][co64][k32]        (k<16 = ci natural, else 0)
//   WD2  @ 37888  [t9][kc2][co32][ci32]  (ci permuted: l4(kc*32+ci))
//   WD3  @ 56320  [t9][co16][ci32]       (taps FLIPPED: src 8-t; ci perm l2; co>=3 -> 0)
//   cn (fp32, 512) @ byte offset 121856 within wbuf

__global__ void zero_k(float* __restrict__ acc) {
    acc[blockIdx.x * 256 + threadIdx.x] = 0.f;
}

__global__ __launch_bounds__(256) void prep_k(
        const float* __restrict__ ew1, const float* __restrict__ ew2,
        const float* __restrict__ dw1, const float* __restrict__ dw2,
        const float* __restrict__ dw3, const float* __restrict__ cb,
        ushort_t* __restrict__ wt, float* __restrict__ cn) {
    int idx = blockIdx.x * 256 + threadIdx.x;
    if (idx < 1024) {
        int co = idx >> 5, k = idx & 31;
        wt[idx] = (k < 27) ? f2bf(ew1[co * 27 + k]) : (ushort_t)0;
    } else if (idx < 19456) {
        int i = idx - 1024;
        int t = i >> 11, co = (i >> 5) & 63, ci = i & 31;
        int lci = ((ci & 1) << 4) | (ci >> 1);                 // l2 (conv1 U=2)
        wt[idx] = f2bf(ew2[co * 288 + lci * 9 + t]);
    } else if (idx < 37888) {
        int i = idx - 19456;
        int t = i >> 11, co = (i >> 5) & 63, k = i & 31;
        wt[idx] = (k < 16) ? f2bf(dw1[k * 576 + co * 9 + t]) : (ushort_t)0;
    } else if (idx < 56320) {
        int i = idx - 37888;
        int t = i >> 11, kc = (i >> 10) & 1, co = (i >> 5) & 31, ci = i & 31;
        int m = kc * 32 + ci;
        int lci = ((m & 3) << 4) | (m >> 2);                   // l4 (dec1 U=4)
        wt[idx] = f2bf(dw2[lci * 288 + co * 9 + t]);
    } else if (idx < 60928) {
        int i = idx - 56320;
        int t = i >> 9, co = (i >> 5) & 15, ci = i & 31;
        int lci = ((ci & 1) << 4) | (ci >> 1);                 // l2 (dec2 U=2)
        wt[idx] = (co < 3) ? f2bf(dw3[lci * 27 + co * 9 + (8 - t)]) : (ushort_t)0;
    } else if (idx < 61440) {
        int k = idx - 60928;
        float s = 0.f;
        #pragma unroll
        for (int d = 0; d < 16; ++d) { float v = cb[k * 16 + d]; s += v * v; }
        cn[k] = s;
    }
}

// ---------------- zero the pad borders of d1p (one block per image) ---------
__global__ __launch_bounds__(256) void pad_k(ushort_t* __restrict__ d1p) {
    const int img = blockIdx.x, tid = threadIdx.x;
    const uint4 z = (uint4){0, 0, 0, 0};
    uint4* b1 = (uint4*)(d1p + (size_t)img * 1065024);   // 129*129*64 elems
    for (int i = tid; i < 1032; i += 256) b1[132096 + i] = z;   // row 128
    for (int i = tid; i < 1024; i += 256) {                     // col 128
        int r = i >> 3, u = i & 7;
        b1[(r * 129 + 128) * 8 + u] = z;
    }
}

// ---------------- conv1 MFMA: x NCHW fp32 -> a1 [B,128,128,32] (interleaved)
__global__ __launch_bounds__(256, 4) void conv1_k(const float* __restrict__ x,
        const ushort_t* __restrict__ wt, const float* __restrict__ bias,
        ushort_t* __restrict__ a1) {
    const int L = xcd_chunk(blockIdx.y, gridDim.y);
    const int b = L >> 7, oh = L & 127;
    const int tid = threadIdx.x;
    __shared__ __align__(16) ushort_t sX[9 * 264];   // [ci*3+kh][iw+1 (258 used)]
    __shared__ int sOff[32];
    for (int i = tid; i < 9 * 264 / 2; i += 256) ((unsigned*)sX)[i] = 0u;
    if (tid < 32) {
        int k = tid, off = 0;
        if (k < 27) { int ci = k / 9, r9 = k % 9, kh = r9 / 3, kw = r9 % 3;
                      off = (ci * 3 + kh) * 264 + kw; }
        sOff[tid] = off;
    }
    __syncthreads();
    #pragma unroll
    for (int it = 0; it < 9; ++it) {
        int slot = it * 256 + tid;                  // 2304 = 3ci * 3kh * 256iw
        int ci = slot / 768, r = slot % 768, kh = r >> 8, iw = r & 255;
        int ih = 2 * oh + kh - 1;
        float v = ((unsigned)ih < 256u) ? x[(long)(b * 3 + ci) * 65536 + ih * 256 + iw] : 0.f;
        sX[(ci * 3 + kh) * 264 + iw + 1] = f2bf(v);
    }
    __syncthreads();
    const int lane = tid & 63, wave = tid >> 6, q = lane >> 4, n16 = lane & 15;
    bf16x8 Bw[2];
    #pragma unroll
    for (int u = 0; u < 2; ++u)
        Bw[u] = *(const bf16x8*)(wt + (u * 16 + n16) * 32 + q * 8);
    f32x4 acc[2][2];
    #pragma unroll
    for (int u = 0; u < 2; ++u) {
        float bz = bias[u * 16 + n16];
        acc[0][u] = (f32x4){bz, bz, bz, bz};
        acc[1][u] = (f32x4){bz, bz, bz, bz};
    }
    #pragma unroll
    for (int mf = 0; mf < 2; ++mf) {
        const int m2 = 2 * (wave * 32 + mf * 16 + n16);
        ushort_t av[8];
        #pragma unroll
        for (int j = 0; j < 8; ++j) {
            int k = q * 8 + j;
            av[j] = (k < 27) ? sX[sOff[k] + m2] : (ushort_t)0;
        }
        bf16x8 A = *(bf16x8*)av;
        #pragma unroll
        for (int u = 0; u < 2; ++u)
            acc[mf][u] = __builtin_amdgcn_mfma_f32_16x16x32_bf16(A, Bw[u], acc[mf][u], 0, 0, 0);
    }
    #pragma unroll
    for (int mf = 0; mf < 2; ++mf)
        #pragma unroll
        for (int r = 0; r < 4; ++r) {
            int ow = wave * 32 + mf * 16 + q * 4 + r;
            *(unsigned*)(a1 + ((long)(b * 128 + oh) * 128 + ow) * 32 + n16 * 2) =
                pack2r(acc[mf][0][r], acc[mf][1][r]);
        }
}

// ---------------- conv2 MFMA: a1 -> a2 [B,64,64,64] (interleaved) -----------
__global__ __launch_bounds__(256, 4) void conv2_k(const ushort_t* __restrict__ a1,
        const ushort_t* __restrict__ wt, const float* __restrict__ bias,
        ushort_t* __restrict__ a2) {
    const int L = xcd_chunk(blockIdx.y, gridDim.y);
    const int b = L >> 6, oh = L & 63;
    const int tid = threadIdx.x;
    // parity-split: [kh3][p2][c66][ci32 pad40]
    __shared__ __align__(16) ushort_t sA[3 * 2 * 66 * 40];
    uint4* z4 = (uint4*)sA;
    #pragma unroll
    for (int it = 0; it < 8; ++it) {
        int slot = it * 256 + tid;
        if (slot < 1980) z4[slot] = (uint4){0, 0, 0, 0};
    }
    __syncthreads();
    #pragma unroll
    for (int it = 0; it < 6; ++it) {
        int slot = it * 256 + tid;                    // 1536 = 3kh*128iw*4
        if (slot < 1536) {
            int kh = slot >> 9, rem = slot & 511, iw = rem >> 2, ci8 = (rem & 3) << 3;
            int ih = 2 * oh + kh - 1;
            if ((unsigned)ih < 128u) {
                uint4 v = *(const uint4*)(a1 + ((long)(b * 128 + ih) * 128 + iw) * 32 + ci8);
                int idx = iw + 2, p = idx & 1, c = idx >> 1;
                *(uint4*)&sA[((kh * 2 + p) * 66 + c) * 40 + ci8] = v;
            }
        }
    }
    __syncthreads();
    const int lane = tid & 63, wave = tid >> 6, q = lane >> 4, n16 = lane & 15;
    f32x4 acc[4];
    #pragma unroll
    for (int u = 0; u < 4; ++u) {
        float bz = bias[u * 16 + n16];
        acc[u] = (f32x4){bz, bz, bz, bz};
    }
    const int ow = wave * 16 + n16;   // A row (m)
    #pragma unroll
    for (int t = 0; t < 9; ++t) {
        const int kh = t / 3, kw = t % 3;
        const int p = (kw == 1) ? 0 : 1;
        const int c = (kw == 0) ? ow : ow + 1;
        bf16x8 A = *(bf16x8*)&sA[((kh * 2 + p) * 66 + c) * 40 + q * 8];
        #pragma unroll
        for (int u = 0; u < 4; ++u) {
            bf16x8 B = *(const bf16x8*)(wt + 1024 + t * 2048 + (u * 16 + n16) * 32 + q * 8);
            acc[u] = __builtin_amdgcn_mfma_f32_16x16x32_bf16(A, B, acc[u], 0, 0, 0);
        }
    }
    #pragma unroll
    for (int r = 0; r < 4; ++r) {
        int owo = wave * 16 + q * 4 + r;
        uint2 pk;
        pk.x = pack2r(acc[0][r], acc[1][r]);
        pk.y = pack2r(acc[2][r], acc[3][r]);
        *(uint2*)(a2 + ((long)(b * 64 + oh) * 64 + owo) * 64 + n16 * 4) = pk;
    }
}

// ---------------- conv3 (1x1) + VQ + loss, 2 px/thread ----------------------
__global__ __launch_bounds__(256) void conv3_vq_k(const ushort_t* __restrict__ a2,
        const float* __restrict__ w3, const float* __restrict__ b3,
        const float* __restrict__ cb, const float* __restrict__ cn,
        ushort_t* __restrict__ e, float* __restrict__ acc) {
    const int base = blockIdx.x * 512 + threadIdx.x;   // px0 = base, px1 = base+256
    __shared__ float sred[4];
    float z[2][16];
    #pragma unroll
    for (int p = 0; p < 2; ++p)
        #pragma unroll
        for (int d = 0; d < 16; ++d) z[p][d] = b3[d];
    #pragma unroll
    for (int p = 0; p < 2; ++p) {
        const ushort_t* arow = a2 + (long)(base + p * 256) * 64;
        #pragma unroll
        for (int c8 = 0; c8 < 8; ++c8) {
            uint4 raw = *(const uint4*)(arow + c8 * 8);
            ushort_t us[8];
            *(uint4*)us = raw;
            #pragma unroll
            for (int j = 0; j < 8; ++j) {
                int m = c8 * 8 + j;
                int lci = ((m & 3) << 4) | (m >> 2);          // l4
                float a = bf2f(us[j]);
                #pragma unroll
                for (int d = 0; d < 16; ++d)
                    z[p][d] = fmaf(a, w3[d * 64 + lci], z[p][d]);
            }
        }
    }
    const float4* cb4 = (const float4*)cb;
    float best0 = 1e30f, best1 = 1e30f; int bi0 = 0, bi1 = 0;
    for (int k = 0; k < 512; ++k) {
        float4 c0 = cb4[k * 4 + 0], c1 = cb4[k * 4 + 1];
        float4 c2 = cb4[k * 4 + 2], c3 = cb4[k * 4 + 3];
        float nk = cn[k];
        float d0 = z[0][0]*c0.x + z[0][1]*c0.y + z[0][2]*c0.z + z[0][3]*c0.w
                 + z[0][4]*c1.x + z[0][5]*c1.y + z[0][6]*c1.z + z[0][7]*c1.w
                 + z[0][8]*c2.x + z[0][9]*c2.y + z[0][10]*c2.z + z[0][11]*c2.w
                 + z[0][12]*c3.x + z[0][13]*c3.y + z[0][14]*c3.z + z[0][15]*c3.w;
        float d1 = z[1][0]*c0.x + z[1][1]*c0.y + z[1][2]*c0.z + z[1][3]*c0.w
                 + z[1][4]*c1.x + z[1][5]*c1.y + z[1][6]*c1.z + z[1][7]*c1.w
                 + z[1][8]*c2.x + z[1][9]*c2.y + z[1][10]*c2.z + z[1][11]*c2.w
                 + z[1][12]*c3.x + z[1][13]*c3.y + z[1][14]*c3.z + z[1][15]*c3.w;
        float dist0 = nk - 2.f * d0, dist1 = nk - 2.f * d1;
        if (dist0 < best0) { best0 = dist0; bi0 = k; }
        if (dist1 < best1) { best1 = dist1; bi1 = k; }
    }
    float lsum = 0.f;
    #pragma unroll
    for (int d = 0; d < 16; ++d) {
        float q0 = cb[bi0 * 16 + d], q1 = cb[bi1 * 16 + d];
        float f0 = q0 - z[0][d], f1 = q1 - z[1][d];
        lsum += f0 * f0 + f1 * f1;
        e[(long)base * 16 + d] = f2bf(q0);
        e[(long)(base + 256) * 16 + d] = f2bf(q1);
    }
    #pragma unroll
    for (int off = 32; off > 0; off >>= 1) lsum += __shfl_down(lsum, off, 64);
    if ((threadIdx.x & 63) == 0) sred[threadIdx.x >> 6] = lsum;
    __syncthreads();
    if (threadIdx.x == 0)
        atomicAdd(&acc[(blockIdx.x & 63) << 5],
                  sred[0] + sred[1] + sred[2] + sred[3]);
}

// ---------------- dec1 MFMA: e -> d1p [B,129,129,64] (interleaved) ----------
__global__ __launch_bounds__(256, 4) void dec1_k(const ushort_t* __restrict__ e,
        const ushort_t* __restrict__ wt, const float* __restrict__ bias,
        ushort_t* __restrict__ d1p) {
    const int L = xcd_chunk(blockIdx.y, gridDim.y);
    const int b = L >> 6, i = L & 63;
    const int tid = threadIdx.x;
    __shared__ __align__(16) ushort_t sE[2 * 66 * 24];  // [dh2][j66][ci16 pad24]
    uint4* z4 = (uint4*)sE;
    #pragma unroll
    for (int it = 0; it < 2; ++it) {
        int slot = it * 256 + tid;
        if (slot < 396) z4[slot] = (uint4){0, 0, 0, 0};
    }
    __syncthreads();
    {
        int dh = tid >> 7, rem = tid & 127, j = rem >> 1, ci8 = (rem & 1) * 8;
        if (i + dh < 64) {
            uint4 v = *(const uint4*)(e + ((long)((b * 64 + i + dh) * 64 + j)) * 16 + ci8);
            *(uint4*)&sE[(dh * 66 + j) * 24 + ci8] = v;
        }
    }
    __syncthreads();
    const int lane = tid & 63, wave = tid >> 6, q = lane >> 4, n16 = lane & 15;
    f32x4 acc[4][4];   // [class ph*2+pw][ntile]
    #pragma unroll
    for (int u = 0; u < 4; ++u) {
        float bz = bias[u * 16 + n16];
        #pragma unroll
        for (int c = 0; c < 4; ++c) acc[c][u] = (f32x4){bz, bz, bz, bz};
    }
    const int jl = wave * 16 + n16;
    #pragma unroll
    for (int t = 0; t < 9; ++t) {
        const int kh = t / 3, kw = t % 3;
        const int dh = (kh == 0) ? 1 : 0, dw = (kw == 0) ? 1 : 0;
        const int cls = ((kh != 1) ? 2 : 0) | ((kw != 1) ? 1 : 0);
        bf16x8 A = *(bf16x8*)&sE[(dh * 66 + jl + dw) * 24 + (q & 1) * 8];
        #pragma unroll
        for (int u = 0; u < 4; ++u) {
            bf16x8 B = *(const bf16x8*)(wt + 19456 + t * 2048 + (u * 16 + n16) * 32 + q * 8);
            acc[cls][u] = __builtin_amdgcn_mfma_f32_16x16x32_bf16(A, B, acc[cls][u], 0, 0, 0);
        }
    }
    #pragma unroll
    for (int ph = 0; ph < 2; ++ph)
        #pragma unroll
        for (int pw = 0; pw < 2; ++pw)
            #pragma unroll
            for (int r = 0; r < 4; ++r) {
                int oh = 2 * i + ph;
                int ow = 2 * (wave * 16 + q * 4 + r) + pw;
                uint2 pk;
                pk.x = pack2r(acc[ph * 2 + pw][0][r], acc[ph * 2 + pw][1][r]);
                pk.y = pack2r(acc[ph * 2 + pw][2][r], acc[ph * 2 + pw][3][r]);
                *(uint2*)(d1p + (size_t)b * 1065024 + ((long)oh * 129 + ow) * 64 + n16 * 4) = pk;
            }
}

// ---------------- dec23: fused convT(64->32,s2) + conv(32->3) + MSE ---------
// Block: output rows 4*i4..4*i4+3, cols j0..j0+127 (j0 = bx*128).
// Stage 1 (R14+R20): wave = one a-row, 5 cells, class-sequential acc reuse.
// (dh,dw)=(0,0) A-fragments hoisted into A00[2][5] once per wave (taps
// 4,5,7,8). R22: __launch_bounds__(256,1) — empirically the 2nd arg is
// doubled into waves-per-eu (budget 512/2N); N=1 gives ~256-reg budget so
// A00 stays in registers (N=3 gave budget 84 -> spill). HW occupancy is
// LDS-capped at 3 blocks/CU either way.
// Stage 2 (R16): kw=1 frags from sT + DPP row_ror for kw=0/2; border init.
__global__ __launch_bounds__(256, 1) void dec23_k(const ushort_t* __restrict__ d1p,
        const ushort_t* __restrict__ wt, const float* __restrict__ db2,
        const float* __restrict__ db3, const float* __restrict__ x,
        float* __restrict__ acc) {
    const int flat = blockIdx.y * 2 + blockIdx.x;
    const int L = xcd_chunk(flat, gridDim.y * 2);
    const int bx = L & 1, byl = L >> 1;
    const int b = byl >> 6, i4 = byl & 63;
    const int j0 = bx << 7;
    const int tid = threadIdx.x;
    const int lane = tid & 63, wave = tid >> 6, q = lane >> 4, n16 = lane & 15;

    __shared__ __align__(16) ushort_t sT[6 * 132 * 32];   // [R'6][c'132][ch32] 50688 B
    __shared__ float sred[4];

    // ---- targeted border init (interior is fully written by stage 1) ----
    // unwritten-but-read: col 0 (bx=0), col 129 (bx=1), row 0 (i4=0), row 5 (i4=63)
    {
        unsigned* sw = (unsigned*)sT;
        if (tid < 96) {
            int r6 = tid >> 4, w16 = tid & 15;
            int c = (bx == 0) ? 0 : 129;
            sw[r6 * 2112 + c * 16 + w16] = 0u;
        }
        if (i4 == 0)
            for (int i = tid; i < 2080; i += 256) sw[i] = 0u;
        if (i4 == 63)
            for (int i = tid; i < 2080; i += 256) sw[5 * 2112 + i] = 0u;
    }
    __syncthreads();

    // ---- stage 1: dec2 into sT (class-sequential, one a-row per wave) ----
    const int bb0 = (j0 >> 1) - 1;
    const ushort_t* dbase = d1p + (size_t)b * 1065024;
    const int aidx = wave;
    const int a = 2 * i4 + aidx - 1;
    const bool doP0 = (aidx != 0);    // d2 row 2a+0 in tile?
    const bool doP1 = (aidx != 3);    // d2 row 2a+1 in tile?
    // row pointers, OOB rows -> zero pad row 128
    int r0 = a, r1 = a + 1;
    r0 = ((unsigned)r0 <= 128u) ? r0 : 128;
    r1 = ((unsigned)r1 <= 128u) ? r1 : 128;
    const ushort_t* rowp0 = dbase + (long)r0 * 8256;   // 129*64
    const ushort_t* rowp1 = dbase + (long)r1 * 8256;
    // per-lane col element-offsets, OOB cols -> zero pad col 128
    int colo[5][2];
    #pragma unroll
    for (int cell = 0; cell < 5; ++cell)
        #pragma unroll
        for (int dw = 0; dw < 2; ++dw) {
            int col = bb0 + cell * 16 + n16 + dw;
            colo[cell][dw] = (((unsigned)col <= 128u) ? col : 128) * 64;
        }
    const float bz0 = db2[n16], bz1 = db2[16 + n16];
    f32x4 a5[2][5];                                    // [u][cell], per class

    // R20: hoisted (dh,dw)=(0,0) fragments — used by taps 4,5,7,8
    bf16x8 A00[2][5];                                  // [kc][cell]
    #pragma unroll
    for (int kc = 0; kc < 2; ++kc)
        #pragma unroll
        for (int cell = 0; cell < 5; ++cell)
            A00[kc][cell] = *(const bf16x8*)(rowp0 + colo[cell][0] + kc * 32 + q * 8);

#define INIT5()                                                                     \
    _Pragma("unroll")                                                               \
    for (int cell = 0; cell < 5; ++cell) {                                          \
        a5[0][cell] = (f32x4){bz0, bz0, bz0, bz0};                                  \
        a5[1][cell] = (f32x4){bz1, bz1, bz1, bz1};                                  \
    }
#define TAP5(T, DH, DW)                                                             \
    {                                                                               \
        const ushort_t* wb = wt + 37888 + (T) * 2048;                               \
        const ushort_t* rp = (DH) ? rowp1 : rowp0;                                  \
        _Pragma("unroll")                                                           \
        for (int kc = 0; kc < 2; ++kc) {                                            \
            bf16x8 B0 = *(const bf16x8*)(wb + kc * 1024 + n16 * 32 + q * 8);        \
            bf16x8 B1 = *(const bf16x8*)(wb + kc * 1024 + (16 + n16) * 32 + q * 8); \
            _Pragma("unroll")                                                       \
            for (int cell = 0; cell < 5; ++cell) {                                  \
                bf16x8 Av = *(const bf16x8*)(rp + colo[cell][DW] + kc * 32 + q * 8);\
                a5[0][cell] = __builtin_amdgcn_mfma_f32_16x16x32_bf16(              \
                    Av, B0, a5[0][cell], 0, 0, 0);                                  \
                a5[1][cell] = __builtin_amdgcn_mfma_f32_16x16x32_bf16(              \
                    Av, B1, a5[1][cell], 0, 0, 0);                                  \
            }                                                                       \
        }                                                                           \
    }
#define TAP5H(T)                                                                    \
    {                                                                               \
        const ushort_t* wb = wt + 37888 + (T) * 2048;                               \
        _Pragma("unroll")                                                           \
        for (int kc = 0; kc < 2; ++kc) {                                            \
            bf16x8 B0 = *(const bf16x8*)(wb + kc * 1024 + n16 * 32 + q * 8);        \
            bf16x8 B1 = *(const bf16x8*)(wb + kc * 1024 + (16 + n16) * 32 + q * 8); \
            _Pragma("unroll")                                                       \
            for (int cell = 0; cell < 5; ++cell) {                                  \
                a5[0][cell] = __builtin_amdgcn_mfma_f32_16x16x32_bf16(              \
                    A00[kc][cell], B0, a5[0][cell], 0, 0, 0);                       \
                a5[1][cell] = __builtin_amdgcn_mfma_f32_16x16x32_bf16(              \
                    A00[kc][cell], B1, a5[1][cell], 0, 0, 0);                       \
            }                                                                       \
        }                                                                           \
    }
#define EPI5(PH, PW)                                                                \
    {                                                                               \
        int R = 2 * a + (PH);                                                       \
        if ((unsigned)R < 256u) {                                                   \
            int Rp = R - 4 * i4 + 1;                                                \
            _Pragma("unroll")                                                       \
            for (int cell = 0; cell < 5; ++cell)                                    \
                _Pragma("unroll")                                                   \
                for (int r = 0; r < 4; ++r) {                                       \
                    int lq = cell * 16 + q * 4 + r;                                 \
                    int cp = 2 * lq + (PW) - 1;                                     \
                    int cg = 2 * (bb0 + lq) + (PW);                                 \
                    if ((unsigned)cg < 256u && (unsigned)cp < 130u)                 \
                        *(unsigned*)&sT[Rp * 4224 + cp * 32 + n16 * 2] =            \
                            pack2r(a5[0][cell][r], a5[1][cell][r]);                 \
                }                                                                   \
        }                                                                           \
    }
    // taps by class: cls = (kh!=1)*2 | (kw!=1); dh=(kh==0), dw=(kw==0)
    // (0,0)-taps (4,5,7,8) use hoisted A00 — one per class.
    if (doP0) {
        INIT5(); TAP5H(4); EPI5(0, 0);                             // cls0: (1,1)
        INIT5(); TAP5(3, 0, 1); TAP5H(5); EPI5(0, 1);              // cls1: (1,0),(1,2)
    }
    if (doP1) {
        INIT5(); TAP5(1, 1, 0); TAP5H(7); EPI5(1, 0);              // cls2: (0,1),(2,1)
        INIT5(); TAP5(0, 1, 1); TAP5(2, 1, 0); TAP5(6, 0, 1); TAP5H(8);
        EPI5(1, 1);                                                // cls3: corners
    }
#undef INIT5
#undef TAP5
#undef TAP5H
#undef EPI5
    __syncthreads();

    // ---- stage 2: dec3 conv + MSE (wave -> row oh, cols j0..j0+127) ----
    float bz3 = (n16 < 3) ? db3[n16] : 0.f;
    f32x4 a4[8];
    #pragma unroll
    for (int mf = 0; mf < 8; ++mf) a4[mf] = (f32x4){bz3, bz3, bz3, bz3};
    const int oh = 4 * i4 + wave;
    const bool is_l0 = (n16 == 0), is_l15 = (n16 == 15);
    #pragma unroll
    for (int kh = 0; kh < 3; ++kh) {
        const ushort_t* srow = &sT[(wave + kh) * 4224];
        bf16x8 Bk0 = *(const bf16x8*)(wt + 56320 + (kh * 3 + 0) * 512 + n16 * 32 + q * 8);
        bf16x8 Bk1 = *(const bf16x8*)(wt + 56320 + (kh * 3 + 1) * 512 + n16 * 32 + q * 8);
        bf16x8 Bk2 = *(const bf16x8*)(wt + 56320 + (kh * 3 + 2) * 512 + n16 * 32 + q * 8);
        // kw=1 fragments (c = m+1) + edge fragments
        bf16x8 G[8];
        #pragma unroll
        for (int mf = 0; mf < 8; ++mf)
            G[mf] = *(const bf16x8*)(srow + (mf * 16 + n16 + 1) * 32 + q * 8);
        bf16x8 E  = *(const bf16x8*)(srow + n16 * 32 + q * 8);          // lane0 -> c=0
        bf16x8 E2 = *(const bf16x8*)(srow + (114 + n16) * 32 + q * 8);  // lane15 -> c=129
        #pragma unroll
        for (int mf = 0; mf < 8; ++mf)
            a4[mf] = __builtin_amdgcn_mfma_f32_16x16x32_bf16(G[mf], Bk1, a4[mf], 0, 0, 0);
        // kw=0 (c = m): lane n takes lane n-1's G; lane0 patched from prev frag
        bf16x8 P = E;
        #pragma unroll
        for (int mf = 0; mf < 8; ++mf) {
            bf16x8 Qm; ROR_FRAG(Qm, G[mf], 0x121);      // ror:1 -> src[n-1]
            bf16x8 kw0 = is_l0 ? P : Qm;
            a4[mf] = __builtin_amdgcn_mfma_f32_16x16x32_bf16(kw0, Bk0, a4[mf], 0, 0, 0);
            P = Qm;
        }
        // kw=2 (c = m+2): lane n takes lane n+1's G; lane15 patched from next frag
        P = E2;
        #pragma unroll
        for (int mf = 7; mf >= 0; --mf) {
            bf16x8 Rm; ROR_FRAG(Rm, G[mf], 0x12F);      // ror:15 -> src[n+1]
            bf16x8 kw2 = is_l15 ? P : Rm;
            a4[mf] = __builtin_amdgcn_mfma_f32_16x16x32_bf16(kw2, Bk2, a4[mf], 0, 0, 0);
            P = Rm;
        }
    }
    float lsum = 0.f;
    if (n16 < 3) {
        const float* xrow = x + ((long)(b * 3 + n16) * 256 + oh) * 256 + j0;
        #pragma unroll
        for (int mf = 0; mf < 8; ++mf)
            #pragma unroll
            for (int r = 0; r < 4; ++r) {
                int ow = mf * 16 + q * 4 + r;
                float df = a4[mf][r] - xrow[ow];
                lsum += df * df;
            }
    }
    #pragma unroll
    for (int off = 32; off > 0; off >>= 1) lsum += __shfl_down(lsum, off, 64);
    if (lane == 0) sred[wave] = lsum;
    __syncthreads();
    if (tid == 0)
        atomicAdd(&acc[2048 + ((byl & 63) << 5)],
                  sred[0] + sred[1] + sred[2] + sred[3]);
}

__global__ void finalize_k(const float* __restrict__ acc, float* __restrict__ out) {
    int t = threadIdx.x;                 // 64 threads
    float v = acc[t << 5];
    float m = acc[2048 + (t << 5)];
    #pragma unroll
    for (int off = 32; off > 0; off >>= 1) {
        v += __shfl_down(v, off, 64);
        m += __shfl_down(m, off, 64);
    }
    if (t == 0) {
        float eq  = 1.25f * v / 4194304.f;     // 262144 px * 16 d
        float mse = m / 12582912.f;            // 64 * 3 * 256 * 256
        out[0] = eq;
        out[1] = mse;
        out[2] = mse;
    }
}

extern "C" void kernel_launch(void* const* d_in, const int* in_sizes, int n_in,
                              void* d_out, int out_size, void* d_ws, size_t ws_size,
                              hipStream_t stream) {
    (void)in_sizes; (void)n_in; (void)out_size;
    const float* x   = (const float*)d_in[0];
    const float* ew1 = (const float*)d_in[1];
    const float* eb1 = (const float*)d_in[2];
    const float* ew2 = (const float*)d_in[3];
    const float* eb2 = (const float*)d_in[4];
    const float* ew3 = (const float*)d_in[5];
    const float* eb3 = (const float*)d_in[6];
    const float* cb  = (const float*)d_in[7];
    const float* dw1 = (const float*)d_in[8];
    const float* db1 = (const float*)d_in[9];
    const float* dw2 = (const float*)d_in[10];
    const float* db2 = (const float*)d_in[11];
    const float* dw3 = (const float*)d_in[12];
    const float* db3 = (const float*)d_in[13];
    float* out = (float*)d_out;

    // workspace: acc 16384 B | wbuf 131072 B | e C*131072 | rgn C*2130048
    // need(C) = 147456 + C*2261120   (C=64 -> ~144.9 MB)
    int C = 64;
    while (C > 1 && (size_t)147456 + (size_t)C * 2261120UL > ws_size) C >>= 1;

    char* base = (char*)d_ws;
    float*    acc = (float*)base;                            // 4096 floats
    ushort_t* wt  = (ushort_t*)(base + 16384);
    float*    cn  = (float*)(base + 16384 + 121856);
    ushort_t* e   = (ushort_t*)(base + 147456);
    char*     rgn = base + 147456 + (size_t)C * 131072UL;
    ushort_t* a1  = (ushort_t*)rgn;
    ushort_t* a2  = (ushort_t*)(rgn + (size_t)C * 1048576UL);
    ushort_t* d1p = (ushort_t*)rgn;                          // reuse (a1/a2 dead)

    zero_k<<<16, 256, 0, stream>>>(acc);
    prep_k<<<240, 256, 0, stream>>>(ew1, ew2, dw1, dw2, dw3, cb, wt, cn);

    for (int b0 = 0; b0 < 64; b0 += C) {
        const float* xc = x + (size_t)b0 * 196608UL;
        conv1_k   <<<dim3(1, C * 128), 256, 0, stream>>>(xc,  wt, eb1, a1);
        conv2_k   <<<dim3(1, C * 64),  256, 0, stream>>>(a1,  wt, eb2, a2);
        conv3_vq_k<<<dim3(C * 8),      256, 0, stream>>>(a2,  ew3, eb3, cb, cn, e, acc);
        pad_k     <<<dim3(C),          256, 0, stream>>>(d1p);
        dec1_k    <<<dim3(1, C * 64),  256, 0, stream>>>(e,   wt, db1, d1p);
        dec23_k   <<<dim3(2, C * 64),  256, 0, stream>>>(d1p, wt, db2, db3, xc, acc);
    }
    finalize_k<<<1, 64, 0, stream>>>(acc, out);
}

// Round 12
// 625.974 us; speedup vs baseline: 1.2492x; 1.0041x over previous
//
#include <hip/hip_runtime.h>
#include <hip/hip_bf16.h>

// VQ-VAE forward — NHWC bf16 intermediates, MFMA (16x16x32 bf16) for all convs.
// Outputs: [1.25*vq_mse, recon_mse, recon_mse]
//
// MFMA lane layouts (gfx950, HW-verified per guide):
//   A: m = lane&15, k = (lane>>4)*8 + j     (8 bf16 / lane)
//   B: n = lane&15, k = (lane>>4)*8 + j
//   D: n = lane&15, m = (lane>>4)*4 + reg   (4 f32 / lane)
//
// CHANNEL-INTERLEAVED storage: a producer with U=Cc/16 tiles stores tile u,
// column n16 (logical co = u*16+n16) at memory channel m = n16*U+u; consumers
// permute ci in weight prep: logical l(m) = (m%U)*16 + m/U.
//
// dec2+dec3 FUSED (dec23_k). R13: 1 atomic/block (580->409). R14: class-
// sequential stage 1 (409->323). R15: XCD swizzle. R16: DPP kw-dedup (319).
// R19: binding resource = VMEM load-instruction throughput (~47cy/instr/CU).
// R20: hoist (0,0) A-frags, A-loads 90->60 (307, spilled at VGPR=84).
// R22: launch_bounds mapping DECODED: (256,N) -> VGPR budget 512/(2N) AND
// residency cap ~2N waves/EU. N=1: budget 256 -> no spill (VGPR 116, WRITE
// 131MB->0.26MB) BUT residency capped ~2 blocks/CU (occ 31.6->21.6%): 296us.
// R23: N=2 = the sweet spot. Budget 128 >= need (116) -> no spill;
// residency cap 4 waves/EU >= LDS cap (3 blocks/CU) -> occupancy back to
// ~31%. First round combining: load-count cut + spill-free + 3-block
// residency. Canaries: WRITE_SIZE (spill), OccupancyPercent (residency).
//
// d1p [B][129][129][64]: interior (0,0)..(127,127); pad row/col 128 = 0.

typedef __attribute__((ext_vector_type(8))) short bf16x8;
typedef __attribute__((ext_vector_type(4))) float f32x4;
typedef __attribute__((ext_vector_type(4))) int i32x4;
typedef unsigned short ushort_t;

__device__ __forceinline__ ushort_t f2bf(float v) {
    __hip_bfloat16 h = __float2bfloat16(v);
    return *(ushort_t*)&h;
}
__device__ __forceinline__ float bf2f(ushort_t u) {
    __hip_bfloat16 h = *(__hip_bfloat16*)&u;
    return __bfloat162float(h);
}
__device__ __forceinline__ unsigned pack2r(float a, float b) {   // relu+pack
    return (unsigned)f2bf(fmaxf(a, 0.f)) | ((unsigned)f2bf(fmaxf(b, 0.f)) << 16);
}
// XCD-chunked bijective remap (requires nwg%8==0).
__device__ __forceinline__ int xcd_chunk(int flat, int nwg) {
    return (flat & 7) * (nwg >> 3) + (flat >> 3);
}
// DPP row-rotate of a 16B fragment within each 16-lane row.
// row_ror:N -> dst[n] = src[(n-N) mod 16].  0x121 = ror:1, 0x12F = ror:15.
#define ROR_FRAG(dst, src, CTRL)                                        \
    {                                                                   \
        i32x4 _a = __builtin_bit_cast(i32x4, src), _r;                  \
        _r[0] = __builtin_amdgcn_mov_dpp(_a[0], CTRL, 0xF, 0xF, false); \
        _r[1] = __builtin_amdgcn_mov_dpp(_a[1], CTRL, 0xF, 0xF, false); \
        _r[2] = __builtin_amdgcn_mov_dpp(_a[2], CTRL, 0xF, 0xF, false); \
        _r[3] = __builtin_amdgcn_mov_dpp(_a[3], CTRL, 0xF, 0xF, false); \
        dst = __builtin_bit_cast(bf16x8, _r);                           \
    }

// Accumulator layout (fp32, 4096 floats = 16 KB at workspace base):
//   vq  partials: acc[slot*32],        slot = 0..63   (128 B apart)
//   mse partials: acc[2048 + slot*32], slot = 0..63
//
// Transformed-weight layout in wbuf (elements of bf16, at base+16384):
//   W1T  @ 0      [co32][k32]            (k=ci*9+kh*3+kw, pad 27->32)
//   W2T  @ 1024   [t9][co64][ci32]       (ci permuted: l2(ci))
//   WD1  @ 19456  [t9][co64][k32]        (k<16 = ci natural, else 0)
//   WD2  @ 37888  [t9][kc2][co32][ci32]  (ci permuted: l4(kc*32+ci))
//   WD3  @ 56320  [t9][co16][ci32]       (taps FLIPPED: src 8-t; ci perm l2; co>=3 -> 0)
//   cn (fp32, 512) @ byte offset 121856 within wbuf

__global__ void zero_k(float* __restrict__ acc) {
    acc[blockIdx.x * 256 + threadIdx.x] = 0.f;
}

__global__ __launch_bounds__(256) void prep_k(
        const float* __restrict__ ew1, const float* __restrict__ ew2,
        const float* __restrict__ dw1, const float* __restrict__ dw2,
        const float* __restrict__ dw3, const float* __restrict__ cb,
        ushort_t* __restrict__ wt, float* __restrict__ cn) {
    int idx = blockIdx.x * 256 + threadIdx.x;
    if (idx < 1024) {
        int co = idx >> 5, k = idx & 31;
        wt[idx] = (k < 27) ? f2bf(ew1[co * 27 + k]) : (ushort_t)0;
    } else if (idx < 19456) {
        int i = idx - 1024;
        int t = i >> 11, co = (i >> 5) & 63, ci = i & 31;
        int lci = ((ci & 1) << 4) | (ci >> 1);                 // l2 (conv1 U=2)
        wt[idx] = f2bf(ew2[co * 288 + lci * 9 + t]);
    } else if (idx < 37888) {
        int i = idx - 19456;
        int t = i >> 11, co = (i >> 5) & 63, k = i & 31;
        wt[idx] = (k < 16) ? f2bf(dw1[k * 576 + co * 9 + t]) : (ushort_t)0;
    } else if (idx < 56320) {
        int i = idx - 37888;
        int t = i >> 11, kc = (i >> 10) & 1, co = (i >> 5) & 31, ci = i & 31;
        int m = kc * 32 + ci;
        int lci = ((m & 3) << 4) | (m >> 2);                   // l4 (dec1 U=4)
        wt[idx] = f2bf(dw2[lci * 288 + co * 9 + t]);
    } else if (idx < 60928) {
        int i = idx - 56320;
        int t = i >> 9, co = (i >> 5) & 15, ci = i & 31;
        int lci = ((ci & 1) << 4) | (ci >> 1);                 // l2 (dec2 U=2)
        wt[idx] = (co < 3) ? f2bf(dw3[lci * 27 + co * 9 + (8 - t)]) : (ushort_t)0;
    } else if (idx < 61440) {
        int k = idx - 60928;
        float s = 0.f;
        #pragma unroll
        for (int d = 0; d < 16; ++d) { float v = cb[k * 16 + d]; s += v * v; }
        cn[k] = s;
    }
}

// ---------------- zero the pad borders of d1p (one block per image) ---------
__global__ __launch_bounds__(256) void pad_k(ushort_t* __restrict__ d1p) {
    const int img = blockIdx.x, tid = threadIdx.x;
    const uint4 z = (uint4){0, 0, 0, 0};
    uint4* b1 = (uint4*)(d1p + (size_t)img * 1065024);   // 129*129*64 elems
    for (int i = tid; i < 1032; i += 256) b1[132096 + i] = z;   // row 128
    for (int i = tid; i < 1024; i += 256) {                     // col 128
        int r = i >> 3, u = i & 7;
        b1[(r * 129 + 128) * 8 + u] = z;
    }
}

// ---------------- conv1 MFMA: x NCHW fp32 -> a1 [B,128,128,32] (interleaved)
__global__ __launch_bounds__(256, 4) void conv1_k(const float* __restrict__ x,
        const ushort_t* __restrict__ wt, const float* __restrict__ bias,
        ushort_t* __restrict__ a1) {
    const int L = xcd_chunk(blockIdx.y, gridDim.y);
    const int b = L >> 7, oh = L & 127;
    const int tid = threadIdx.x;
    __shared__ __align__(16) ushort_t sX[9 * 264];   // [ci*3+kh][iw+1 (258 used)]
    __shared__ int sOff[32];
    for (int i = tid; i < 9 * 264 / 2; i += 256) ((unsigned*)sX)[i] = 0u;
    if (tid < 32) {
        int k = tid, off = 0;
        if (k < 27) { int ci = k / 9, r9 = k % 9, kh = r9 / 3, kw = r9 % 3;
                      off = (ci * 3 + kh) * 264 + kw; }
        sOff[tid] = off;
    }
    __syncthreads();
    #pragma unroll
    for (int it = 0; it < 9; ++it) {
        int slot = it * 256 + tid;                  // 2304 = 3ci * 3kh * 256iw
        int ci = slot / 768, r = slot % 768, kh = r >> 8, iw = r & 255;
        int ih = 2 * oh + kh - 1;
        float v = ((unsigned)ih < 256u) ? x[(long)(b * 3 + ci) * 65536 + ih * 256 + iw] : 0.f;
        sX[(ci * 3 + kh) * 264 + iw + 1] = f2bf(v);
    }
    __syncthreads();
    const int lane = tid & 63, wave = tid >> 6, q = lane >> 4, n16 = lane & 15;
    bf16x8 Bw[2];
    #pragma unroll
    for (int u = 0; u < 2; ++u)
        Bw[u] = *(const bf16x8*)(wt + (u * 16 + n16) * 32 + q * 8);
    f32x4 acc[2][2];
    #pragma unroll
    for (int u = 0; u < 2; ++u) {
        float bz = bias[u * 16 + n16];
        acc[0][u] = (f32x4){bz, bz, bz, bz};
        acc[1][u] = (f32x4){bz, bz, bz, bz};
    }
    #pragma unroll
    for (int mf = 0; mf < 2; ++mf) {
        const int m2 = 2 * (wave * 32 + mf * 16 + n16);
        ushort_t av[8];
        #pragma unroll
        for (int j = 0; j < 8; ++j) {
            int k = q * 8 + j;
            av[j] = (k < 27) ? sX[sOff[k] + m2] : (ushort_t)0;
        }
        bf16x8 A = *(bf16x8*)av;
        #pragma unroll
        for (int u = 0; u < 2; ++u)
            acc[mf][u] = __builtin_amdgcn_mfma_f32_16x16x32_bf16(A, Bw[u], acc[mf][u], 0, 0, 0);
    }
    #pragma unroll
    for (int mf = 0; mf < 2; ++mf)
        #pragma unroll
        for (int r = 0; r < 4; ++r) {
            int ow = wave * 32 + mf * 16 + q * 4 + r;
            *(unsigned*)(a1 + ((long)(b * 128 + oh) * 128 + ow) * 32 + n16 * 2) =
                pack2r(acc[mf][0][r], acc[mf][1][r]);
        }
}

// ---------------- conv2 MFMA: a1 -> a2 [B,64,64,64] (interleaved) -----------
__global__ __launch_bounds__(256, 4) void conv2_k(const ushort_t* __restrict__ a1,
        const ushort_t* __restrict__ wt, const float* __restrict__ bias,
        ushort_t* __restrict__ a2) {
    const int L = xcd_chunk(blockIdx.y, gridDim.y);
    const int b = L >> 6, oh = L & 63;
    const int tid = threadIdx.x;
    // parity-split: [kh3][p2][c66][ci32 pad40]
    __shared__ __align__(16) ushort_t sA[3 * 2 * 66 * 40];
    uint4* z4 = (uint4*)sA;
    #pragma unroll
    for (int it = 0; it < 8; ++it) {
        int slot = it * 256 + tid;
        if (slot < 1980) z4[slot] = (uint4){0, 0, 0, 0};
    }
    __syncthreads();
    #pragma unroll
    for (int it = 0; it < 6; ++it) {
        int slot = it * 256 + tid;                    // 1536 = 3kh*128iw*4
        if (slot < 1536) {
            int kh = slot >> 9, rem = slot & 511, iw = rem >> 2, ci8 = (rem & 3) << 3;
            int ih = 2 * oh + kh - 1;
            if ((unsigned)ih < 128u) {
                uint4 v = *(const uint4*)(a1 + ((long)(b * 128 + ih) * 128 + iw) * 32 + ci8);
                int idx = iw + 2, p = idx & 1, c = idx >> 1;
                *(uint4*)&sA[((kh * 2 + p) * 66 + c) * 40 + ci8] = v;
            }
        }
    }
    __syncthreads();
    const int lane = tid & 63, wave = tid >> 6, q = lane >> 4, n16 = lane & 15;
    f32x4 acc[4];
    #pragma unroll
    for (int u = 0; u < 4; ++u) {
        float bz = bias[u * 16 + n16];
        acc[u] = (f32x4){bz, bz, bz, bz};
    }
    const int ow = wave * 16 + n16;   // A row (m)
    #pragma unroll
    for (int t = 0; t < 9; ++t) {
        const int kh = t / 3, kw = t % 3;
        const int p = (kw == 1) ? 0 : 1;
        const int c = (kw == 0) ? ow : ow + 1;
        bf16x8 A = *(bf16x8*)&sA[((kh * 2 + p) * 66 + c) * 40 + q * 8];
        #pragma unroll
        for (int u = 0; u < 4; ++u) {
            bf16x8 B = *(const bf16x8*)(wt + 1024 + t * 2048 + (u * 16 + n16) * 32 + q * 8);
            acc[u] = __builtin_amdgcn_mfma_f32_16x16x32_bf16(A, B, acc[u], 0, 0, 0);
        }
    }
    #pragma unroll
    for (int r = 0; r < 4; ++r) {
        int owo = wave * 16 + q * 4 + r;
        uint2 pk;
        pk.x = pack2r(acc[0][r], acc[1][r]);
        pk.y = pack2r(acc[2][r], acc[3][r]);
        *(uint2*)(a2 + ((long)(b * 64 + oh) * 64 + owo) * 64 + n16 * 4) = pk;
    }
}

// ---------------- conv3 (1x1) + VQ + loss, 2 px/thread ----------------------
__global__ __launch_bounds__(256) void conv3_vq_k(const ushort_t* __restrict__ a2,
        const float* __restrict__ w3, const float* __restrict__ b3,
        const float* __restrict__ cb, const float* __restrict__ cn,
        ushort_t* __restrict__ e, float* __restrict__ acc) {
    const int base = blockIdx.x * 512 + threadIdx.x;   // px0 = base, px1 = base+256
    __shared__ float sred[4];
    float z[2][16];
    #pragma unroll
    for (int p = 0; p < 2; ++p)
        #pragma unroll
        for (int d = 0; d < 16; ++d) z[p][d] = b3[d];
    #pragma unroll
    for (int p = 0; p < 2; ++p) {
        const ushort_t* arow = a2 + (long)(base + p * 256) * 64;
        #pragma unroll
        for (int c8 = 0; c8 < 8; ++c8) {
            uint4 raw = *(const uint4*)(arow + c8 * 8);
            ushort_t us[8];
            *(uint4*)us = raw;
            #pragma unroll
            for (int j = 0; j < 8; ++j) {
                int m = c8 * 8 + j;
                int lci = ((m & 3) << 4) | (m >> 2);          // l4
                float a = bf2f(us[j]);
                #pragma unroll
                for (int d = 0; d < 16; ++d)
                    z[p][d] = fmaf(a, w3[d * 64 + lci], z[p][d]);
            }
        }
    }
    const float4* cb4 = (const float4*)cb;
    float best0 = 1e30f, best1 = 1e30f; int bi0 = 0, bi1 = 0;
    for (int k = 0; k < 512; ++k) {
        float4 c0 = cb4[k * 4 + 0], c1 = cb4[k * 4 + 1];
        float4 c2 = cb4[k * 4 + 2], c3 = cb4[k * 4 + 3];
        float nk = cn[k];
        float d0 = z[0][0]*c0.x + z[0][1]*c0.y + z[0][2]*c0.z + z[0][3]*c0.w
                 + z[0][4]*c1.x + z[0][5]*c1.y + z[0][6]*c1.z + z[0][7]*c1.w
                 + z[0][8]*c2.x + z[0][9]*c2.y + z[0][10]*c2.z + z[0][11]*c2.w
                 + z[0][12]*c3.x + z[0][13]*c3.y + z[0][14]*c3.z + z[0][15]*c3.w;
        float d1 = z[1][0]*c0.x + z[1][1]*c0.y + z[1][2]*c0.z + z[1][3]*c0.w
                 + z[1][4]*c1.x + z[1][5]*c1.y + z[1][6]*c1.z + z[1][7]*c1.w
                 + z[1][8]*c2.x + z[1][9]*c2.y + z[1][10]*c2.z + z[1][11]*c2.w
                 + z[1][12]*c3.x + z[1][13]*c3.y + z[1][14]*c3.z + z[1][15]*c3.w;
        float dist0 = nk - 2.f * d0, dist1 = nk - 2.f * d1;
        if (dist0 < best0) { best0 = dist0; bi0 = k; }
        if (dist1 < best1) { best1 = dist1; bi1 = k; }
    }
    float lsum = 0.f;
    #pragma unroll
    for (int d = 0; d < 16; ++d) {
        float q0 = cb[bi0 * 16 + d], q1 = cb[bi1 * 16 + d];
        float f0 = q0 - z[0][d], f1 = q1 - z[1][d];
        lsum += f0 * f0 + f1 * f1;
        e[(long)base * 16 + d] = f2bf(q0);
        e[(long)(base + 256) * 16 + d] = f2bf(q1);
    }
    #pragma unroll
    for (int off = 32; off > 0; off >>= 1) lsum += __shfl_down(lsum, off, 64);
    if ((threadIdx.x & 63) == 0) sred[threadIdx.x >> 6] = lsum;
    __syncthreads();
    if (threadIdx.x == 0)
        atomicAdd(&acc[(blockIdx.x & 63) << 5],
                  sred[0] + sred[1] + sred[2] + sred[3]);
}

// ---------------- dec1 MFMA: e -> d1p [B,129,129,64] (interleaved) ----------
__global__ __launch_bounds__(256, 4) void dec1_k(const ushort_t* __restrict__ e,
        const ushort_t* __restrict__ wt, const float* __restrict__ bias,
        ushort_t* __restrict__ d1p) {
    const int L = xcd_chunk(blockIdx.y, gridDim.y);
    const int b = L >> 6, i = L & 63;
    const int tid = threadIdx.x;
    __shared__ __align__(16) ushort_t sE[2 * 66 * 24];  // [dh2][j66][ci16 pad24]
    uint4* z4 = (uint4*)sE;
    #pragma unroll
    for (int it = 0; it < 2; ++it) {
        int slot = it * 256 + tid;
        if (slot < 396) z4[slot] = (uint4){0, 0, 0, 0};
    }
    __syncthreads();
    {
        int dh = tid >> 7, rem = tid & 127, j = rem >> 1, ci8 = (rem & 1) * 8;
        if (i + dh < 64) {
            uint4 v = *(const uint4*)(e + ((long)((b * 64 + i + dh) * 64 + j)) * 16 + ci8);
            *(uint4*)&sE[(dh * 66 + j) * 24 + ci8] = v;
        }
    }
    __syncthreads();
    const int lane = tid & 63, wave = tid >> 6, q = lane >> 4, n16 = lane & 15;
    f32x4 acc[4][4];   // [class ph*2+pw][ntile]
    #pragma unroll
    for (int u = 0; u < 4; ++u) {
        float bz = bias[u * 16 + n16];
        #pragma unroll
        for (int c = 0; c < 4; ++c) acc[c][u] = (f32x4){bz, bz, bz, bz};
    }
    const int jl = wave * 16 + n16;
    #pragma unroll
    for (int t = 0; t < 9; ++t) {
        const int kh = t / 3, kw = t % 3;
        const int dh = (kh == 0) ? 1 : 0, dw = (kw == 0) ? 1 : 0;
        const int cls = ((kh != 1) ? 2 : 0) | ((kw != 1) ? 1 : 0);
        bf16x8 A = *(bf16x8*)&sE[(dh * 66 + jl + dw) * 24 + (q & 1) * 8];
        #pragma unroll
        for (int u = 0; u < 4; ++u) {
            bf16x8 B = *(const bf16x8*)(wt + 19456 + t * 2048 + (u * 16 + n16) * 32 + q * 8);
            acc[cls][u] = __builtin_amdgcn_mfma_f32_16x16x32_bf16(A, B, acc[cls][u], 0, 0, 0);
        }
    }
    #pragma unroll
    for (int ph = 0; ph < 2; ++ph)
        #pragma unroll
        for (int pw = 0; pw < 2; ++pw)
            #pragma unroll
            for (int r = 0; r < 4; ++r) {
                int oh = 2 * i + ph;
                int ow = 2 * (wave * 16 + q * 4 + r) + pw;
                uint2 pk;
                pk.x = pack2r(acc[ph * 2 + pw][0][r], acc[ph * 2 + pw][1][r]);
                pk.y = pack2r(acc[ph * 2 + pw][2][r], acc[ph * 2 + pw][3][r]);
                *(uint2*)(d1p + (size_t)b * 1065024 + ((long)oh * 129 + ow) * 64 + n16 * 4) = pk;
            }
}

// ---------------- dec23: fused convT(64->32,s2) + conv(32->3) + MSE ---------
// Block: output rows 4*i4..4*i4+3, cols j0..j0+127 (j0 = bx*128).
// Stage 1 (R14+R20): wave = one a-row, 5 cells, class-sequential acc reuse.
// (dh,dw)=(0,0) A-fragments hoisted into A00[2][5] once per wave (taps
// 4,5,7,8). R23: __launch_bounds__(256,2) — per the decoded mapping,
// budget 512/4=128 >= need (116, no spill) AND residency cap 4 waves/EU
// >= LDS cap (3 blocks/CU), restoring ~31% occupancy lost at N=1.
// Stage 2 (R16): kw=1 frags from sT + DPP row_ror for kw=0/2; border init.
__global__ __launch_bounds__(256, 2) void dec23_k(const ushort_t* __restrict__ d1p,
        const ushort_t* __restrict__ wt, const float* __restrict__ db2,
        const float* __restrict__ db3, const float* __restrict__ x,
        float* __restrict__ acc) {
    const int flat = blockIdx.y * 2 + blockIdx.x;
    const int L = xcd_chunk(flat, gridDim.y * 2);
    const int bx = L & 1, byl = L >> 1;
    const int b = byl >> 6, i4 = byl & 63;
    const int j0 = bx << 7;
    const int tid = threadIdx.x;
    const int lane = tid & 63, wave = tid >> 6, q = lane >> 4, n16 = lane & 15;

    __shared__ __align__(16) ushort_t sT[6 * 132 * 32];   // [R'6][c'132][ch32] 50688 B
    __shared__ float sred[4];

    // ---- targeted border init (interior is fully written by stage 1) ----
    // unwritten-but-read: col 0 (bx=0), col 129 (bx=1), row 0 (i4=0), row 5 (i4=63)
    {
        unsigned* sw = (unsigned*)sT;
        if (tid < 96) {
            int r6 = tid >> 4, w16 = tid & 15;
            int c = (bx == 0) ? 0 : 129;
            sw[r6 * 2112 + c * 16 + w16] = 0u;
        }
        if (i4 == 0)
            for (int i = tid; i < 2080; i += 256) sw[i] = 0u;
        if (i4 == 63)
            for (int i = tid; i < 2080; i += 256) sw[5 * 2112 + i] = 0u;
    }
    __syncthreads();

    // ---- stage 1: dec2 into sT (class-sequential, one a-row per wave) ----
    const int bb0 = (j0 >> 1) - 1;
    const ushort_t* dbase = d1p + (size_t)b * 1065024;
    const int aidx = wave;
    const int a = 2 * i4 + aidx - 1;
    const bool doP0 = (aidx != 0);    // d2 row 2a+0 in tile?
    const bool doP1 = (aidx != 3);    // d2 row 2a+1 in tile?
    // row pointers, OOB rows -> zero pad row 128
    int r0 = a, r1 = a + 1;
    r0 = ((unsigned)r0 <= 128u) ? r0 : 128;
    r1 = ((unsigned)r1 <= 128u) ? r1 : 128;
    const ushort_t* rowp0 = dbase + (long)r0 * 8256;   // 129*64
    const ushort_t* rowp1 = dbase + (long)r1 * 8256;
    // per-lane col element-offsets, OOB cols -> zero pad col 128
    int colo[5][2];
    #pragma unroll
    for (int cell = 0; cell < 5; ++cell)
        #pragma unroll
        for (int dw = 0; dw < 2; ++dw) {
            int col = bb0 + cell * 16 + n16 + dw;
            colo[cell][dw] = (((unsigned)col <= 128u) ? col : 128) * 64;
        }
    const float bz0 = db2[n16], bz1 = db2[16 + n16];
    f32x4 a5[2][5];                                    // [u][cell], per class

    // R20: hoisted (dh,dw)=(0,0) fragments — used by taps 4,5,7,8
    bf16x8 A00[2][5];                                  // [kc][cell]
    #pragma unroll
    for (int kc = 0; kc < 2; ++kc)
        #pragma unroll
        for (int cell = 0; cell < 5; ++cell)
            A00[kc][cell] = *(const bf16x8*)(rowp0 + colo[cell][0] + kc * 32 + q * 8);

#define INIT5()                                                                     \
    _Pragma("unroll")                                                               \
    for (int cell = 0; cell < 5; ++cell) {                                          \
        a5[0][cell] = (f32x4){bz0, bz0, bz0, bz0};                                  \
        a5[1][cell] = (f32x4){bz1, bz1, bz1, bz1};                                  \
    }
#define TAP5(T, DH, DW)                                                             \
    {                                                                               \
        const ushort_t* wb = wt + 37888 + (T) * 2048;                               \
        const ushort_t* rp = (DH) ? rowp1 : rowp0;                                  \
        _Pragma("unroll")                                                           \
        for (int kc = 0; kc < 2; ++kc) {                                            \
            bf16x8 B0 = *(const bf16x8*)(wb + kc * 1024 + n16 * 32 + q * 8);        \
            bf16x8 B1 = *(const bf16x8*)(wb + kc * 1024 + (16 + n16) * 32 + q * 8); \
            _Pragma("unroll")                                                       \
            for (int cell = 0; cell < 5; ++cell) {                                  \
                bf16x8 Av = *(const bf16x8*)(rp + colo[cell][DW] + kc * 32 + q * 8);\
                a5[0][cell] = __builtin_amdgcn_mfma_f32_16x16x32_bf16(              \
                    Av, B0, a5[0][cell], 0, 0, 0);                                  \
                a5[1][cell] = __builtin_amdgcn_mfma_f32_16x16x32_bf16(              \
                    Av, B1, a5[1][cell], 0, 0, 0);                                  \
            }                                                                       \
        }                                                                           \
    }
#define TAP5H(T)                                                                    \
    {                                                                               \
        const ushort_t* wb = wt + 37888 + (T) * 2048;                               \
        _Pragma("unroll")                                                           \
        for (int kc = 0; kc < 2; ++kc) {                                            \
            bf16x8 B0 = *(const bf16x8*)(wb + kc * 1024 + n16 * 32 + q * 8);        \
            bf16x8 B1 = *(const bf16x8*)(wb + kc * 1024 + (16 + n16) * 32 + q * 8); \
            _Pragma("unroll")                                                       \
            for (int cell = 0; cell < 5; ++cell) {                                  \
                a5[0][cell] = __builtin_amdgcn_mfma_f32_16x16x32_bf16(              \
                    A00[kc][cell], B0, a5[0][cell], 0, 0, 0);                       \
                a5[1][cell] = __builtin_amdgcn_mfma_f32_16x16x32_bf16(              \
                    A00[kc][cell], B1, a5[1][cell], 0, 0, 0);                       \
            }                                                                       \
        }                                                                           \
    }
#define EPI5(PH, PW)                                                                \
    {                                                                               \
        int R = 2 * a + (PH);                                                       \
        if ((unsigned)R < 256u) {                                                   \
            int Rp = R - 4 * i4 + 1;                                                \
            _Pragma("unroll")                                                       \
            for (int cell = 0; cell < 5; ++cell)                                    \
                _Pragma("unroll")                                                   \
                for (int r = 0; r < 4; ++r) {                                       \
                    int lq = cell * 16 + q * 4 + r;                                 \
                    int cp = 2 * lq + (PW) - 1;                                     \
                    int cg = 2 * (bb0 + lq) + (PW);                                 \
                    if ((unsigned)cg < 256u && (unsigned)cp < 130u)                 \
                        *(unsigned*)&sT[Rp * 4224 + cp * 32 + n16 * 2] =            \
                            pack2r(a5[0][cell][r], a5[1][cell][r]);                 \
                }                                                                   \
        }                                                                           \
    }
    // taps by class: cls = (kh!=1)*2 | (kw!=1); dh=(kh==0), dw=(kw==0)
    // (0,0)-taps (4,5,7,8) use hoisted A00 — one per class.
    if (doP0) {
        INIT5(); TAP5H(4); EPI5(0, 0);                             // cls0: (1,1)
        INIT5(); TAP5(3, 0, 1); TAP5H(5); EPI5(0, 1);              // cls1: (1,0),(1,2)
    }
    if (doP1) {
        INIT5(); TAP5(1, 1, 0); TAP5H(7); EPI5(1, 0);              // cls2: (0,1),(2,1)
        INIT5(); TAP5(0, 1, 1); TAP5(2, 1, 0); TAP5(6, 0, 1); TAP5H(8);
        EPI5(1, 1);                                                // cls3: corners
    }
#undef INIT5
#undef TAP5
#undef TAP5H
#undef EPI5
    __syncthreads();

    // ---- stage 2: dec3 conv + MSE (wave -> row oh, cols j0..j0+127) ----
    float bz3 = (n16 < 3) ? db3[n16] : 0.f;
    f32x4 a4[8];
    #pragma unroll
    for (int mf = 0; mf < 8; ++mf) a4[mf] = (f32x4){bz3, bz3, bz3, bz3};
    const int oh = 4 * i4 + wave;
    const bool is_l0 = (n16 == 0), is_l15 = (n16 == 15);
    #pragma unroll
    for (int kh = 0; kh < 3; ++kh) {
        const ushort_t* srow = &sT[(wave + kh) * 4224];
        bf16x8 Bk0 = *(const bf16x8*)(wt + 56320 + (kh * 3 + 0) * 512 + n16 * 32 + q * 8);
        bf16x8 Bk1 = *(const bf16x8*)(wt + 56320 + (kh * 3 + 1) * 512 + n16 * 32 + q * 8);
        bf16x8 Bk2 = *(const bf16x8*)(wt + 56320 + (kh * 3 + 2) * 512 + n16 * 32 + q * 8);
        // kw=1 fragments (c = m+1) + edge fragments
        bf16x8 G[8];
        #pragma unroll
        for (int mf = 0; mf < 8; ++mf)
            G[mf] = *(const bf16x8*)(srow + (mf * 16 + n16 + 1) * 32 + q * 8);
        bf16x8 E  = *(const bf16x8*)(srow + n16 * 32 + q * 8);          // lane0 -> c=0
        bf16x8 E2 = *(const bf16x8*)(srow + (114 + n16) * 32 + q * 8);  // lane15 -> c=129
        #pragma unroll
        for (int mf = 0; mf < 8; ++mf)
            a4[mf] = __builtin_amdgcn_mfma_f32_16x16x32_bf16(G[mf], Bk1, a4[mf], 0, 0, 0);
        // kw=0 (c = m): lane n takes lane n-1's G; lane0 patched from prev frag
        bf16x8 P = E;
        #pragma unroll
        for (int mf = 0; mf < 8; ++mf) {
            bf16x8 Qm; ROR_FRAG(Qm, G[mf], 0x121);      // ror:1 -> src[n-1]
            bf16x8 kw0 = is_l0 ? P : Qm;
            a4[mf] = __builtin_amdgcn_mfma_f32_16x16x32_bf16(kw0, Bk0, a4[mf], 0, 0, 0);
            P = Qm;
        }
        // kw=2 (c = m+2): lane n takes lane n+1's G; lane15 patched from next frag
        P = E2;
        #pragma unroll
        for (int mf = 7; mf >= 0; --mf) {
            bf16x8 Rm; ROR_FRAG(Rm, G[mf], 0x12F);      // ror:15 -> src[n+1]
            bf16x8 kw2 = is_l15 ? P : Rm;
            a4[mf] = __builtin_amdgcn_mfma_f32_16x16x32_bf16(kw2, Bk2, a4[mf], 0, 0, 0);
            P = Rm;
        }
    }
    float lsum = 0.f;
    if (n16 < 3) {
        const float* xrow = x + ((long)(b * 3 + n16) * 256 + oh) * 256 + j0;
        #pragma unroll
        for (int mf = 0; mf < 8; ++mf)
            #pragma unroll
            for (int r = 0; r < 4; ++r) {
                int ow = mf * 16 + q * 4 + r;
                float df = a4[mf][r] - xrow[ow];
                lsum += df * df;
            }
    }
    #pragma unroll
    for (int off = 32; off > 0; off >>= 1) lsum += __shfl_down(lsum, off, 64);
    if (lane == 0) sred[wave] = lsum;
    __syncthreads();
    if (tid == 0)
        atomicAdd(&acc[2048 + ((byl & 63) << 5)],
                  sred[0] + sred[1] + sred[2] + sred[3]);
}

__global__ void finalize_k(const float* __restrict__ acc, float* __restrict__ out) {
    int t = threadIdx.x;                 // 64 threads
    float v = acc[t << 5];
    float m = acc[2048 + (t << 5)];
    #pragma unroll
    for (int off = 32; off > 0; off >>= 1) {
        v += __shfl_down(v, off, 64);
        m += __shfl_down(m, off, 64);
    }
    if (t == 0) {
        float eq  = 1.25f * v / 4194304.f;     // 262144 px * 16 d
        float mse = m / 12582912.f;            // 64 * 3 * 256 * 256
        out[0] = eq;
        out[1] = mse;
        out[2] = mse;
    }
}

extern "C" void kernel_launch(void* const* d_in, const int* in_sizes, int n_in,
                              void* d_out, int out_size, void* d_ws, size_t ws_size,
                              hipStream_t stream) {
    (void)in_sizes; (void)n_in; (void)out_size;
    const float* x   = (const float*)d_in[0];
    const float* ew1 = (const float*)d_in[1];
    const float* eb1 = (const float*)d_in[2];
    const float* ew2 = (const float*)d_in[3];
    const float* eb2 = (const float*)d_in[4];
    const float* ew3 = (const float*)d_in[5];
    const float* eb3 = (const float*)d_in[6];
    const float* cb  = (const float*)d_in[7];
    const float* dw1 = (const float*)d_in[8];
    const float* db1 = (const float*)d_in[9];
    const float* dw2 = (const float*)d_in[10];
    const float* db2 = (const float*)d_in[11];
    const float* dw3 = (const float*)d_in[12];
    const float* db3 = (const float*)d_in[13];
    float* out = (float*)d_out;

    // workspace: acc 16384 B | wbuf 131072 B | e C*131072 | rgn C*2130048
    // need(C) = 147456 + C*2261120   (C=64 -> ~144.9 MB)
    int C = 64;
    while (C > 1 && (size_t)147456 + (size_t)C * 2261120UL > ws_size) C >>= 1;

    char* base = (char*)d_ws;
    float*    acc = (float*)base;                            // 4096 floats
    ushort_t* wt  = (ushort_t*)(base + 16384);
    float*    cn  = (float*)(base + 16384 + 121856);
    ushort_t* e   = (ushort_t*)(base + 147456);
    char*     rgn = base + 147456 + (size_t)C * 131072UL;
    ushort_t* a1  = (ushort_t*)rgn;
    ushort_t* a2  = (ushort_t*)(rgn + (size_t)C * 1048576UL);
    ushort_t* d1p = (ushort_t*)rgn;                          // reuse (a1/a2 dead)

    zero_k<<<16, 256, 0, stream>>>(acc);
    prep_k<<<240, 256, 0, stream>>>(ew1, ew2, dw1, dw2, dw3, cb, wt, cn);

    for (int b0 = 0; b0 < 64; b0 += C) {
        const float* xc = x + (size_t)b0 * 196608UL;
        conv1_k   <<<dim3(1, C * 128), 256, 0, stream>>>(xc,  wt, eb1, a1);
        conv2_k   <<<dim3(1, C * 64),  256, 0, stream>>>(a1,  wt, eb2, a2);
        conv3_vq_k<<<dim3(C * 8),      256, 0, stream>>>(a2,  ew3, eb3, cb, cn, e, acc);
        pad_k     <<<dim3(C),          256, 0, stream>>>(d1p);
        dec1_k    <<<dim3(1, C * 64),  256, 0, stream>>>(e,   wt, db1, d1p);
        dec23_k   <<<dim3(2, C * 64),  256, 0, stream>>>(d1p, wt, db2, db3, xc, acc);
    }
    finalize_k<<<1, 64, 0, stream>>>(acc, out);
}